// Round 7
// baseline (471.329 us; speedup 1.0000x reference)
//
#include <hip/hip_runtime.h>

// Problem constants: B=2048, F=64, R=32, P=16, C=128, TAU=2.0
#define B_ 2048
#define YS2 7168   // compact Y stride: wch(1024) vch(1024) vepI(2048) Wk(3072)

typedef unsigned short u16;
typedef unsigned int   u32;
typedef __attribute__((ext_vector_type(2))) float v2f;

__device__ __forceinline__ float bfu(u16 u) {
    u32 i = ((u32)u) << 16; float f; __builtin_memcpy(&f, &i, 4); return f;
}
__device__ __forceinline__ u16 f2bf(float v) {
    u32 iv; __builtin_memcpy(&iv, &v, 4);
    u32 r = (iv + 0x7fffu + ((iv >> 16) & 1u)) >> 16;
    return (u16)r;
}
__device__ __forceinline__ float sigm(float x) { return 1.f / (1.f + __expf(-x)); }
__device__ __forceinline__ float lsg(float x) {
    return fminf(x, 0.f) - log1pf(__expf(-fabsf(x)));
}

template<bool F32> __device__ __forceinline__ float LD(const void* p, int e) {
    if (F32) return ((const float*)p)[e];
    return bfu(((const u16*)p)[e]);
}
template<bool F32> __device__ __forceinline__ float2 LD2(const void* p, int e) { // e even
    if (F32) { const float* q = (const float*)p; return make_float2(q[e], q[e + 1]); }
    u32 w = ((const u32*)p)[e >> 1];
    u32 lo = w << 16, hi = w & 0xffff0000u; float a, b;
    __builtin_memcpy(&a, &lo, 4); __builtin_memcpy(&b, &hi, 4);
    return make_float2(a, b);
}
template<bool F32> __device__ __forceinline__ float4 LD4(const void* p, int e) { // e%4==0
    if (F32) return ((const float4*)p)[e >> 2];
    uint2 w = ((const uint2*)p)[e >> 2];
    u32 a0 = w.x << 16, a1 = w.x & 0xffff0000u, a2 = w.y << 16, a3 = w.y & 0xffff0000u;
    float f0, f1, f2, f3;
    __builtin_memcpy(&f0, &a0, 4); __builtin_memcpy(&f1, &a1, 4);
    __builtin_memcpy(&f2, &a2, 4); __builtin_memcpy(&f3, &a3, 4);
    return make_float4(f0, f1, f2, f3);
}
template<bool F32> __device__ __forceinline__ void ST(void* p, int e, float v) {
    if (F32) ((float*)p)[e] = v; else ((u16*)p)[e] = f2bf(v);
}

struct Args {
    const void *form, *ctx;
    const void *mod_W, *mod_b, *wch_W, *wch_b, *wdl_W, *wdl_b, *wep_W, *wep_b;
    const void *vch_W, *vch_b, *vep_W, *vep_b;
    const void *wnc_W, *wnc_b, *wnd_W, *wnd_b, *wne_W, *wne_b;
    const void *m_W, *m_Wb, *mb_W, *mb_b;
    void* outp;
};

// dtype probe: block-uniform, deterministic. Returns 1 if inputs are fp32.
__device__ __forceinline__ int probe_is_f32(const void* ctx, int t, int* flag_s) {
    if (t == 0) {
        int sane = 0;
        const u16* q = (const u16*)ctx;
        for (int i = 0; i < 64; ++i) {
            u16 u = q[2 * i];
            int ex = (u >> 7) & 0xFF;
            sane += (u == 0 || (ex >= 112 && ex <= 143)) ? 1 : 0;
        }
        *flag_s = (sane < 32) ? 1 : 0;
    }
    __syncthreads();
    return *flag_s;
}

// ============================================================================
// Kernel 1: segment-uniform GEMM, direct from source arrays (no repack).
// Y[b][n], n in [0,7168): [0,1024) wch | [1024,2048) vch |
// [2048,4096) vepI (2048+2u+s <- vep col 4u+2s) | [4096,7168) Wk (k*1024+p*64+f)
// Grid 1792 = 7 chunks x 256 row-blocks; block = 8 rows x 1024 cols;
// thread = 8 rows x 4 cols. Chunk resolved ONCE per block (wave-uniform).
// ============================================================================
template<bool F32, bool MB>
__device__ __forceinline__ float4 ldw(const void* Wp, int soff, int c, int st) {
    if (!MB) return LD4<F32>(Wp, soff + c * st);
    float4 a = LD4<F32>(Wp, soff + c * 4096);
    float4 b = LD4<F32>(Wp, soff + 4 + c * 4096);
    return make_float4(a.x, a.z, b.x, b.z);   // cols 4u, 4u+2, 4(u+1), 4(u+1)+2
}

template<bool F32, bool MB>
__device__ void gemm5_loop(const float* ctx_s, int t, int mb, int outc,
                           const void* Wp, int soff, int st, float4 bv,
                           float* __restrict__ Y) {
    v2f acc[8][2];
    #pragma unroll
    for (int m = 0; m < 8; ++m) {
        acc[m][0].x = bv.x; acc[m][0].y = bv.y;
        acc[m][1].x = bv.z; acc[m][1].y = bv.w;
    }

    float4 w[4];
    #pragma unroll
    for (int j = 0; j < 4; ++j) w[j] = ldw<F32, MB>(Wp, soff, j, st);

    #pragma unroll 1
    for (int c4 = 0; c4 < 128; c4 += 4) {
        float4 wn[4];
        if (c4 + 4 < 128) {
            #pragma unroll
            for (int j = 0; j < 4; ++j) wn[j] = ldw<F32, MB>(Wp, soff, c4 + 4 + j, st);
        }
        #pragma unroll
        for (int m = 0; m < 8; ++m) {
            float4 cv = *(const float4*)&ctx_s[m * 128 + c4];   // uniform -> broadcast
            float cs[4] = {cv.x, cv.y, cv.z, cv.w};
            #pragma unroll
            for (int j = 0; j < 4; ++j) {
                v2f cc; cc.x = cs[j]; cc.y = cs[j];
                v2f w01; w01.x = w[j].x; w01.y = w[j].y;
                v2f w23; w23.x = w[j].z; w23.y = w[j].w;
                acc[m][0] += cc * w01;
                acc[m][1] += cc * w23;
            }
        }
        #pragma unroll
        for (int j = 0; j < 4; ++j) w[j] = wn[j];
    }

    #pragma unroll
    for (int m = 0; m < 8; ++m) {
        float4 s;
        s.x = acc[m][0].x; s.y = acc[m][0].y; s.z = acc[m][1].x; s.w = acc[m][1].y;
        *(float4*)(Y + (size_t)(mb + m) * YS2 + outc) = s;
    }
}

template<bool F32>
__device__ void gemm5_body(float* ctx_s, int t, int blk, const Args& A, float* Y) {
    const int cc = blk % 7;          // chunk id 0..6
    const int mb = (blk / 7) * 8;    // first batch row

    // stage ctx tile [8][128]
    {
        int m = t >> 5, c0 = (t & 31) * 4;
        float4 v = LD4<F32>(A.ctx, (mb + m) * 128 + c0);
        *(float4*)&ctx_s[m * 128 + c0] = v;
    }
    __syncthreads();

    const int outc = cc * 1024 + 4 * t;

    if (cc == 2 || cc == 3) {
        int soff = (cc - 2) * 2048 + 8 * t;
        float4 ba = LD4<F32>(A.vep_b, soff);
        float4 bb = LD4<F32>(A.vep_b, soff + 4);
        float4 bv = make_float4(ba.x, ba.z, bb.x, bb.z);
        gemm5_loop<F32, true>(ctx_s, t, mb, outc, A.vep_W, soff, 4096, bv, Y);
    } else if (cc == 0) {
        gemm5_loop<F32, false>(ctx_s, t, mb, outc, A.wch_W, 4 * t, 1024,
                               LD4<F32>(A.wch_b, 4 * t), Y);
    } else if (cc == 1) {
        gemm5_loop<F32, false>(ctx_s, t, mb, outc, A.vch_W, 4 * t, 1024,
                               LD4<F32>(A.vch_b, 4 * t), Y);
    } else {
        int k = cc - 4;
        gemm5_loop<F32, false>(ctx_s, t, mb, outc, A.m_W, k * 131072 + 4 * t, 1024,
                               LD4<F32>(A.m_Wb, k * 1024 + 4 * t), Y);
    }
}

__global__ __launch_bounds__(256) void gemm5_kernel(Args A, float* Y) {
    __shared__ float ctx_s[8 * 128];
    __shared__ int dt_s;
    const int t = threadIdx.x, blk = blockIdx.x;
    int isf32 = probe_is_f32(A.ctx, t, &dt_s);
    if (isf32) gemm5_body<true>(ctx_s, t, blk, A, Y);
    else       gemm5_body<false>(ctx_s, t, blk, A, Y);
}

// ============================================================================
// Kernel 2: smalls-from-ctx + match + xtab + parallel-gated scan
// LDS (~39.9 KB -> 4 blocks/CU):
//   U[6144]: Wk@0(3072,p64) bk@3072(48) modl@3120(96) form@3312(2112,p33)
//            ctx@5424(128) -> after match phase, U overlaid by xtab[6144]
//   V[3072]: wch@0(1024) vch@1024(1024) rlI@2048(1024) -> gtab[3072] in D
// ============================================================================
struct __align__(16) ScanSmem {
    float U[6144];
    float V[3072];
    float match_s[512];     // [p][r]; later ck@0(96) pos@128(96)
    float wnc_s[64];
    float wep0_s[16], wep2_s[16], wdl_s[16];
    float coef_s[96];       // [sub][rs] (sub 0:ep0, 1:deln, 2:ep2)
    float sc_s[2];          // {w_nodeln, w_noepen}
};

template<bool F32>
__device__ void scan_body(ScanSmem& S, int t, int b, const Args& A, const float* __restrict__ Y) {
    float* Wk_s   = S.U;
    float* bk_s   = S.U + 3072;
    float* modl   = S.U + 3120;
    float* form_s = S.U + 3312;    // pitch 33, 2112 floats
    float* ctx_s  = S.U + 5424;    // 128 floats (dead after smalls)
    float* xtab   = S.U;           // overlay after match phase
    float* wch_s  = S.V;
    float* vch_s  = S.V + 1024;
    float* rlI    = S.V + 2048;    // relu(match*wep) pairs
    float* gtab   = S.V;           // overlay in phase D

    const float* Yr = Y + (size_t)b * YS2;
    const float4* Y4 = (const float4*)Yr;

    const int f_own = t & 63;
    const int fq    = t >> 6;

    // ---- register-cache vep pairs straight from global Y (coalesced b64) ---
    const float2* vep2p = (const float2*)(Yr + 2048);
    v2f vepf[16];
    #pragma unroll
    for (int p = 0; p < 16; ++p) {
        float2 v = vep2p[p * 64 + f_own];
        vepf[p].x = v.x; vepf[p].y = v.y;
    }

    // ---- stage form + ctx + Y segments into LDS ----
    {
        int e0 = b * 2048 + t * 8;
        float4 x = LD4<F32>(A.form, e0);
        float4 y = LD4<F32>(A.form, e0 + 4);
        int f = t >> 2, r0 = (t & 3) * 8;
        float* dst = form_s + f * 33 + r0;
        dst[0] = x.x; dst[1] = x.y; dst[2] = x.z; dst[3] = x.w;
        dst[4] = y.x; dst[5] = y.y; dst[6] = y.z; dst[7] = y.w;
    }
    if (t < 32) {
        float4 v = LD4<F32>(A.ctx, b * 128 + 4 * t);
        *(float4*)&ctx_s[4 * t] = v;
    }
    for (int i = t; i < 768; i += 256) ((float4*)Wk_s)[i] = Y4[1024 + i];    // Wk @4096
    ((float4*)wch_s)[t] = Y4[t];                                             // wch @0
    ((float4*)vch_s)[t] = Y4[256 + t];                                       // vch @1024
    __syncthreads();

    // ---- small linears from ctx (weights L2-resident, same for all blocks) -
    if (t < 96) {
        float a = LD<F32>(A.mod_b, t);
        for (int c = 0; c < 128; ++c) a += ctx_s[c] * LD<F32>(A.mod_W, c * 96 + t);
        modl[t] = a;
    } else if (t < 144) {
        int i = t - 96; int k = i >> 4, p = i & 15;
        float a = LD<F32>(A.mb_b, k * 16 + p);
        for (int c = 0; c < 128; ++c) a += ctx_s[c] * LD<F32>(A.mb_W, (k * 128 + c) * 16 + p);
        bk_s[i] = a;
    } else if (t < 208) {
        int f = t - 144;
        float a = LD<F32>(A.wnc_b, f);
        for (int c = 0; c < 128; ++c) a += ctx_s[c] * LD<F32>(A.wnc_W, c * 64 + f);
        S.wnc_s[f] = __expf(a);
    } else if (t < 224) {
        int p = t - 208;
        float a0 = LD<F32>(A.wep_b, 4 * p), a2 = LD<F32>(A.wep_b, 4 * p + 2);
        for (int c = 0; c < 128; ++c) {
            float cv = ctx_s[c];
            a0 += cv * LD<F32>(A.wep_W, c * 64 + 4 * p);
            a2 += cv * LD<F32>(A.wep_W, c * 64 + 4 * p + 2);
        }
        S.wep0_s[p] = a0; S.wep2_s[p] = a2;
    } else if (t < 240) {
        int p = t - 224;
        float a = LD<F32>(A.wdl_b, p);
        for (int c = 0; c < 128; ++c) a += ctx_s[c] * LD<F32>(A.wdl_W, c * 16 + p);
        S.wdl_s[p] = a;
    } else if (t < 242) {
        const void* W  = (t == 240) ? A.wnd_W : A.wne_W;
        const void* bb = (t == 240) ? A.wnd_b : A.wne_b;
        float a = LD<F32>(bb, 0);
        for (int c = 0; c < 128; ++c) a += ctx_s[c] * LD<F32>(W, c);
        S.sc_s[t - 240] = __expf(a);
    }
    __syncthreads();

    // ---- softmax(6) on mod ----
    if (t < 16) {
        float v[6]; float mx = -1e30f;
        #pragma unroll
        for (int j = 0; j < 6; ++j) { v[j] = modl[t * 6 + j]; mx = fmaxf(mx, v[j]); }
        float s = 0.f;
        #pragma unroll
        for (int j = 0; j < 6; ++j) { v[j] = __expf(v[j] - mx); s += v[j]; }
        float inv = 1.f / s;
        #pragma unroll
        for (int j = 0; j < 6; ++j) modl[t * 6 + j] = v[j] * inv;
    }
    __syncthreads();

    // ---- mod scaling + phase C (match) ----
    if (t < 16) {
        S.wep0_s[t] *= modl[t * 6 + 2];
        S.wep2_s[t] *= modl[t * 6 + 4];
        S.wdl_s[t]  *= modl[t * 6 + 1];
    }
    for (int i = t; i < 1024; i += 256) wch_s[i] *= modl[(i >> 6) * 6];

    const int my_r = t & 31;
    #pragma unroll 1
    for (int it = 0; it < 2; ++it) {
        int idx = t + 256 * it;
        int p = idx >> 5, r = idx & 31;
        float s0 = bk_s[p], s1 = bk_s[16 + p], s2 = bk_s[32 + p];
        const float4* w0 = (const float4*)(Wk_s + p * 64);
        const float4* w1 = (const float4*)(Wk_s + (16 + p) * 64);
        const float4* w2 = (const float4*)(Wk_s + (32 + p) * 64);
        for (int f4 = 0; f4 < 16; ++f4) {
            float a0[4], a1[4], a2[4];
            *(float4*)a0 = w0[f4]; *(float4*)a1 = w1[f4]; *(float4*)a2 = w2[f4];
            #pragma unroll
            for (int j = 0; j < 4; ++j) {
                int f = f4 * 4 + j;
                float f0 = form_s[f * 33 + r];
                float fm = __shfl_up(f0, 1, 32);   if (r == 0)  fm = 0.f;
                float fp = __shfl_down(f0, 1, 32); if (r == 31) fp = 0.f;
                s0 += a0[j] * fm; s1 += a1[j] * f0; s2 += a2[j] * fp;
            }
        }
        S.match_s[p * 32 + r] = __expf(lsg(s0) + lsg(s1) + lsg(s2));
    }
    __syncthreads();

    // ---- coef + rlI precompute + register caching (before U overlay) ----
    if (t < 96) {
        int sub = t >> 5, r = t & 31;
        const float* w = (sub == 0) ? S.wep0_s : (sub == 1) ? S.wdl_s : S.wep2_s;
        float s = 0.f;
        for (int p = 0; p < 16; ++p) s += S.match_s[p * 32 + r] * w[p];
        float cf;
        if (sub == 1) cf = 1.f - sigm(s - S.sc_s[0]);   // 1 - p_deln
        else          cf = sigm(s - S.sc_s[1]);         // p_epen
        S.coef_s[sub * 32 + r] = cf;
    }
    for (int i = t; i < 512; i += 256) {
        int p = i >> 5, r = i & 31;
        float m = S.match_s[p * 32 + r];
        rlI[2 * i]     = fmaxf(m * S.wep0_s[p], 0.f);
        rlI[2 * i + 1] = fmaxf(m * S.wep2_s[p], 0.f);
    }
    float wchf[16], vchf[16];
    #pragma unroll
    for (int p = 0; p < 16; ++p) {
        wchf[p] = wch_s[p * 64 + f_own];
        vchf[p] = vch_s[p * 64 + f_own];
    }
    const float wncf = S.wnc_s[f_own];
    float si_r[8];                                 // form dies at U overlay
    #pragma unroll
    for (int j = 0; j < 8; ++j) si_r[j] = form_s[f_own * 33 + fq * 8 + j];
    __syncthreads();

    // ---- xtab: per-thread fixed f, 8 rs values (overlays U) ----
    #pragma unroll 1
    for (int j = 0; j < 8; ++j) {
        int rs = fq * 8 + j;                       // wave-uniform
        v2f v02; v02.x = 0.f; v02.y = 0.f;
        float sum = 0.f, vs1 = 0.f;
        const v2f* rlp = (const v2f*)(rlI + 2 * rs);
        #pragma unroll
        for (int p = 0; p < 16; ++p) {
            v2f rl = rlp[p * 32];                  // broadcast b64
            v02 += rl * vepf[p];
            float m = S.match_s[p * 32 + rs];      // broadcast b32
            float wc = m * wchf[p];
            sum += wc;
            vs1 += fmaxf(wc, 0.f) * vchf[p];
        }
        float pch = sigm(sum - wncf);
        float si  = si_r[j];
        xtab[0 * 2048 + rs * 64 + f_own] = v02.x;
        xtab[1 * 2048 + rs * 64 + f_own] = si + pch * (vs1 - si);
        xtab[2 * 2048 + rs * 64 + f_own] = v02.y;
    }
    __syncthreads();

    // ---- k-ordered coefs (k = rs*3+sub) + exclusive prefix (posn) ----
    float* ck_s  = S.match_s;        // match dead after xtab
    float* pos_s = S.match_s + 128;
    if (t < 96) ck_s[t] = S.coef_s[(t % 3) * 32 + (t / 3)];
    __syncthreads();
    if (t < 64) {
        float a = ck_s[t];
        float a0 = a;
        #pragma unroll
        for (int d = 1; d < 64; d <<= 1) { float v = __shfl_up(a, d, 64); if (t >= d) a += v; }
        pos_s[t] = a - a0;                          // exclusive prefix
        float carry = __shfl(a, 63, 64);            // inclusive sum of first 64
        float b2 = (t < 32) ? ck_s[64 + t] : 0.f;
        float c2 = b2;
        #pragma unroll
        for (int d = 1; d < 32; d <<= 1) { float v = __shfl_up(c2, d, 32); if ((t & 31) >= d) c2 += v; }
        if (t < 32) pos_s[64 + t] = carry + c2 - b2;
    }
    __syncthreads();

    // ---- gtab[k][r]: all 96 softmax-gates in parallel (overlays V) ----
    #pragma unroll 1
    for (int i = 0; i < 12; ++i) {
        int idx = t + 256 * i;                      // k = idx>>5, r = idx&31
        int k = idx >> 5, r = idx & 31;
        float posn = pos_s[k];
        float pc = fminf(posn, 31.f);
        float ci = floorf(pc + 0.5f);
        float dmin = posn - ci;
        float dd = posn - (float)r;
        float eo = __expf(-2.f * (dd * dd - dmin * dmin));   // exact, max-subtracted
        float Z = eo;
        Z += __shfl_xor(Z, 1, 32);
        Z += __shfl_xor(Z, 2, 32);
        Z += __shfl_xor(Z, 4, 32);
        Z += __shfl_xor(Z, 8, 32);
        Z += __shfl_xor(Z, 16, 32);
        gtab[idx] = ck_s[k] * eo / Z;
    }
    __syncthreads();

    // ---- phase D: pure-throughput blend ----
    const int fgrp = t >> 5;
    v2f o01, o23, o45, o67;
    o01 = 0.f; o23 = 0.f; o45 = 0.f; o67 = 0.f;
    #pragma unroll 1
    for (int rs = 0; rs < 32; ++rs) {
        #pragma unroll
        for (int sub = 0; sub < 3; ++sub) {
            float g = gtab[(rs * 3 + sub) * 32 + my_r];
            v2f gv; gv.x = g; gv.y = g;
            const float4* xb = (const float4*)(xtab + sub * 2048 + rs * 64 + fgrp * 8);
            float4 xa = xb[0], xc = xb[1];
            v2f x01, x23, x45, x67;
            x01.x = xa.x; x01.y = xa.y; x23.x = xa.z; x23.y = xa.w;
            x45.x = xc.x; x45.y = xc.y; x67.x = xc.z; x67.y = xc.w;
            o01 += gv * (x01 - o01);
            o23 += gv * (x23 - o23);
            o45 += gv * (x45 - o45);
            o67 += gv * (x67 - o67);
        }
    }

    float oreg[8] = {o01.x, o01.y, o23.x, o23.y, o45.x, o45.y, o67.x, o67.y};
    #pragma unroll
    for (int i = 0; i < 8; ++i) {
        ST<F32>(A.outp, b * 2048 + (fgrp * 8 + i) * 32 + my_r, oreg[i]);
    }
}

__global__ __launch_bounds__(256) void scan_kernel(Args A, const float* Y) {
    __shared__ ScanSmem S;
    __shared__ int dt_s;
    const int t = threadIdx.x, b = blockIdx.x;
    int isf32 = probe_is_f32(A.ctx, t, &dt_s);
    if (isf32) scan_body<true>(S, t, b, A, Y);
    else       scan_body<false>(S, t, b, A, Y);
}

// ---------------- Last-resort monolithic fallback (round-2, proven) ---------
struct Smem {
    float U[6144];
    float form_s[64 * 33];
    float match_s[512];
    float wch_s[1024];
    float vch_s[1024];
    float vep0_s[1024];
    float vep2_s[1024];
    float wep0_s[16], wep2_s[16], wdl_s[16];
    float wnc_s[64];
    float sc_s[2];
    float ssum_s[96];
};

template<bool F32>
__device__ void mono_body(Smem& S, int t, int b, const Args& A) {
    float* c_s  = S.U;
    float* modl = S.U + 128;
    float* Wk_s = S.U + 224;
    float* bk_s = S.U + 3344;
    float* xtab = S.U;

    if (t < 128) c_s[t] = LD<F32>(A.ctx, b * 128 + t);
    {
        int e0 = b * 2048 + t * 8;
        float4 x = LD4<F32>(A.form, e0);
        float4 y = LD4<F32>(A.form, e0 + 4);
        int f = t >> 2, r0 = (t & 3) * 8;
        float* dst = S.form_s + f * 33 + r0;
        dst[0] = x.x; dst[1] = x.y; dst[2] = x.z; dst[3] = x.w;
        dst[4] = y.x; dst[5] = y.y; dst[6] = y.z; dst[7] = y.w;
    }
    __syncthreads();
    if (t < 96) {
        float a = LD<F32>(A.mod_b, t);
        for (int cc = 0; cc < 128; ++cc) a += c_s[cc] * LD<F32>(A.mod_W, cc * 96 + t);
        modl[t] = a;
    }
    __syncthreads();
    if (t < 16) {
        float v[6]; float mx = -1e30f;
        #pragma unroll
        for (int j = 0; j < 6; ++j) { v[j] = modl[t * 6 + j]; mx = fmaxf(mx, v[j]); }
        float s = 0.f;
        #pragma unroll
        for (int j = 0; j < 6; ++j) { v[j] = __expf(v[j] - mx); s += v[j]; }
        float inv = 1.f / s;
        #pragma unroll
        for (int j = 0; j < 6; ++j) modl[t * 6 + j] = v[j] * inv;
    }
    __syncthreads();
    for (int j = t; j < 512; j += 256) {
        int n0 = j * 2;
        float2 bb = LD2<F32>(A.wch_b, n0);
        float a0 = bb.x, a1 = bb.y;
        for (int cc = 0; cc < 128; ++cc) {
            float2 w = LD2<F32>(A.wch_W, cc * 1024 + n0); float cv = c_s[cc];
            a0 += cv * w.x; a1 += cv * w.y;
        }
        int p = n0 >> 6; float sc = modl[p * 6 + 0];
        S.wch_s[n0] = sc * a0; S.wch_s[n0 + 1] = sc * a1;
    }
    for (int j = t; j < 512; j += 256) {
        int n0 = j * 2;
        float2 bb = LD2<F32>(A.vch_b, n0);
        float a0 = bb.x, a1 = bb.y;
        for (int cc = 0; cc < 128; ++cc) {
            float2 w = LD2<F32>(A.vch_W, cc * 1024 + n0); float cv = c_s[cc];
            a0 += cv * w.x; a1 += cv * w.y;
        }
        S.vch_s[n0] = a0; S.vch_s[n0 + 1] = a1;
    }
    for (int u = t; u < 1024; u += 256) {
        int n0 = u * 4;
        float4 bb = LD4<F32>(A.vep_b, n0);
        float a0 = bb.x, a2 = bb.z;
        for (int cc = 0; cc < 128; ++cc) {
            float4 w = LD4<F32>(A.vep_W, cc * 4096 + n0); float cv = c_s[cc];
            a0 += cv * w.x; a2 += cv * w.z;
        }
        S.vep0_s[u] = a0; S.vep2_s[u] = a2;
    }
    for (int j = t; j < 1536; j += 256) {
        int k  = j >> 9;
        int jj = j & 511;
        int n0 = jj * 2;
        float2 bb = LD2<F32>(A.m_Wb, k * 1024 + n0);
        float a0 = bb.x, a1 = bb.y;
        for (int cc = 0; cc < 128; ++cc) {
            float2 w = LD2<F32>(A.m_W, (k * 128 + cc) * 1024 + n0); float cv = c_s[cc];
            a0 += cv * w.x; a1 += cv * w.y;
        }
        int p = n0 >> 6, f = n0 & 63;
        Wk_s[(k * 16 + p) * 65 + f]     = a0;
        Wk_s[(k * 16 + p) * 65 + f + 1] = a1;
    }
    if (t < 16) {
        int n0 = t * 4;
        float4 bb = LD4<F32>(A.wep_b, n0);
        float a0 = bb.x, a2 = bb.z;
        for (int cc = 0; cc < 128; ++cc) {
            float4 w = LD4<F32>(A.wep_W, cc * 64 + n0); float cv = c_s[cc];
            a0 += cv * w.x; a2 += cv * w.z;
        }
        S.wep0_s[t] = modl[t * 6 + 2] * a0;
        S.wep2_s[t] = modl[t * 6 + 4] * a2;
    } else if (t < 32) {
        int p = t - 16;
        float a = LD<F32>(A.wdl_b, p);
        for (int cc = 0; cc < 128; ++cc) a += c_s[cc] * LD<F32>(A.wdl_W, cc * 16 + p);
        S.wdl_s[p] = modl[p * 6 + 1] * a;
    } else if (t < 96) {
        int f = t - 32;
        float a = LD<F32>(A.wnc_b, f);
        for (int cc = 0; cc < 128; ++cc) a += c_s[cc] * LD<F32>(A.wnc_W, cc * 64 + f);
        S.wnc_s[f] = __expf(a);
    } else if (t < 98) {
        const void* W  = (t == 96) ? A.wnd_W : A.wne_W;
        const void* bb = (t == 96) ? A.wnd_b : A.wne_b;
        float a = LD<F32>(bb, 0);
        for (int cc = 0; cc < 128; ++cc) a += c_s[cc] * LD<F32>(W, cc);
        S.sc_s[t - 96] = __expf(a);
    } else if (t < 146) {
        int i = t - 98;
        int k = i >> 4, p = i & 15;
        float a = LD<F32>(A.mb_b, k * 16 + p);
        for (int cc = 0; cc < 128; ++cc) a += c_s[cc] * LD<F32>(A.mb_W, (k * 128 + cc) * 16 + p);
        bk_s[i] = a;
    }
    __syncthreads();
    for (int idx = t; idx < 512; idx += 256) {
        int p = idx >> 5, r = idx & 31;
        float s0 = bk_s[p], s1 = bk_s[16 + p], s2 = bk_s[32 + p];
        const float* w0 = Wk_s + p * 65;
        const float* w1 = Wk_s + (16 + p) * 65;
        const float* w2 = Wk_s + (32 + p) * 65;
        for (int f = 0; f < 64; ++f) {
            const float* fr = S.form_s + f * 33 + r;
            float fm1 = (r > 0)  ? fr[-1] : 0.f;
            float f0  = fr[0];
            float fp1 = (r < 31) ? fr[1]  : 0.f;
            s0 += w0[f] * fm1; s1 += w1[f] * f0; s2 += w2[f] * fp1;
        }
        S.match_s[p * 32 + r] = __expf(lsg(s0) + lsg(s1) + lsg(s2));
    }
    __syncthreads();
    if (t < 96) {
        int which = t >> 5, r = t & 31;
        const float* w = (which == 0) ? S.wep0_s : (which == 1) ? S.wep2_s : S.wdl_s;
        float s = 0.f;
        for (int p = 0; p < 16; ++p) s += S.match_s[p * 32 + r] * w[p];
        S.ssum_s[which * 32 + r] = s;
    }
    #pragma unroll 1
    for (int q = 0; q < 24; ++q) {
        int idx = t + 256 * q;
        int sub = idx >> 11;
        int rs  = (idx >> 6) & 31;
        int f   = idx & 63;
        float x;
        if (sub == 1) {
            float sum = 0.f, vs = 0.f;
            for (int p = 0; p < 16; ++p) {
                float wc = S.match_s[p * 32 + rs] * S.wch_s[p * 64 + f];
                sum += wc;
                vs  += fmaxf(wc, 0.f) * S.vch_s[p * 64 + f];
            }
            float pch = sigm(sum - S.wnc_s[f]);
            float si  = S.form_s[f * 33 + rs];
            x = si + pch * (vs - si);
        } else {
            const float* wep = (sub == 0) ? S.wep0_s : S.wep2_s;
            const float* vep = (sub == 0) ? S.vep0_s : S.vep2_s;
            float vs = 0.f;
            for (int p = 0; p < 16; ++p) {
                float w = S.match_s[p * 32 + rs] * wep[p];
                vs += fmaxf(w, 0.f) * vep[p * 64 + f];
            }
            x = vs;
        }
        xtab[idx] = x;
    }
    __syncthreads();
    const int my_r = t & 31;
    const int fgrp = t >> 5;
    float oreg[8];
    #pragma unroll
    for (int i = 0; i < 8; ++i) oreg[i] = 0.f;
    float posn = 0.f;
    const float wnd1v = S.sc_s[0];
    const float wne1v = S.sc_s[1];
    for (int rs = 0; rs < 32; ++rs) {
        #pragma unroll
        for (int sub = 0; sub < 3; ++sub) {
            float coef;
            if (sub == 1) coef = 1.f - sigm(S.ssum_s[64 + rs] - wnd1v);
            else          coef = sigm(S.ssum_s[(sub & 2) * 16 + rs] - wne1v);
            float pc = fminf(posn, 31.f);
            int ci = (int)(pc + 0.5f);
            int lo = ci - 4; if (lo < 0)  lo = 0;
            int hi = ci + 4; if (hi > 31) hi = 31;
            float dmin = posn - (float)ci;
            float mx = -2.f * dmin * dmin;
            float Z = 0.f, eo = 0.f;
            for (int r = lo; r <= hi; ++r) {
                float d = posn - (float)r;
                float e = __expf(-2.f * d * d - mx);
                Z += e;
                if (r == my_r) eo = e;
            }
            float g = coef * eo / Z;
            const float* xb = xtab + (sub * 2048 + rs * 64 + fgrp * 8);
            #pragma unroll
            for (int i = 0; i < 8; ++i) oreg[i] += g * (xb[i] - oreg[i]);
            posn += coef;
        }
    }
    #pragma unroll
    for (int i = 0; i < 8; ++i) {
        ST<F32>(A.outp, b * 2048 + (fgrp * 8 + i) * 32 + my_r, oreg[i]);
    }
}

__global__ __launch_bounds__(256) void phon_mono(Args A) {
    __shared__ Smem S;
    __shared__ int dt_s;
    const int t = threadIdx.x, b = blockIdx.x;
    int isf32 = probe_is_f32(A.ctx, t, &dt_s);
    if (isf32) mono_body<true>(S, t, b, A);
    else       mono_body<false>(S, t, b, A);
}

extern "C" void kernel_launch(void* const* d_in, const int* in_sizes, int n_in,
                              void* d_out, int out_size, void* d_ws, size_t ws_size,
                              hipStream_t stream) {
    Args A;
    A.form  = d_in[0];  A.ctx   = d_in[1];
    A.mod_W = d_in[2];  A.mod_b = d_in[3];
    A.wch_W = d_in[4];  A.wch_b = d_in[5];
    A.wdl_W = d_in[6];  A.wdl_b = d_in[7];
    A.wep_W = d_in[8];  A.wep_b = d_in[9];
    A.vch_W = d_in[10]; A.vch_b = d_in[11];
    A.vep_W = d_in[12]; A.vep_b = d_in[13];
    A.wnc_W = d_in[14]; A.wnc_b = d_in[15];
    A.wnd_W = d_in[16]; A.wnd_b = d_in[17];
    A.wne_W = d_in[18]; A.wne_b = d_in[19];
    A.m_W   = d_in[20]; A.m_Wb  = d_in[21];
    A.mb_W  = d_in[22]; A.mb_b  = d_in[23];
    A.outp  = d_out;

    const size_t need = (size_t)B_ * YS2 * sizeof(float);
    if (ws_size >= need) {
        float* Y = (float*)d_ws;
        gemm5_kernel<<<7 * 256, 256, 0, stream>>>(A, Y);
        scan_kernel<<<B_, 256, 0, stream>>>(A, Y);
    } else {
        phon_mono<<<B_, 256, 0, stream>>>(A);
    }
}

// Round 8
// 265.862 us; speedup vs baseline: 1.7728x; 1.7728x over previous
//
#include <hip/hip_runtime.h>

// Problem constants: B=2048, F=64, R=32, P=16, C=128, TAU=2.0
#define B_ 2048
#define YS2 7168   // Y stride: wch(1024) vch(1024) vepI(2048) Wk(3072)
#define NTILES 448 // 7168/16

typedef unsigned short u16;
typedef unsigned int   u32;
typedef __attribute__((ext_vector_type(2))) float v2f;
typedef __attribute__((ext_vector_type(8))) short bf16x8;  // 8 bf16 = 4 VGPR
typedef __attribute__((ext_vector_type(4))) float f32x4;

__device__ __forceinline__ float bfu(u16 u) {
    u32 i = ((u32)u) << 16; float f; __builtin_memcpy(&f, &i, 4); return f;
}
__device__ __forceinline__ u16 f2bf(float v) {
    u32 iv; __builtin_memcpy(&iv, &v, 4);
    u32 r = (iv + 0x7fffu + ((iv >> 16) & 1u)) >> 16;
    return (u16)r;
}
__device__ __forceinline__ float sigm(float x) { return 1.f / (1.f + __expf(-x)); }
__device__ __forceinline__ float lsg(float x) {
    return fminf(x, 0.f) - log1pf(__expf(-fabsf(x)));
}

template<bool F32> __device__ __forceinline__ float LD(const void* p, int e) {
    if (F32) return ((const float*)p)[e];
    return bfu(((const u16*)p)[e]);
}
template<bool F32> __device__ __forceinline__ float2 LD2(const void* p, int e) { // e even
    if (F32) { const float* q = (const float*)p; return make_float2(q[e], q[e + 1]); }
    u32 w = ((const u32*)p)[e >> 1];
    u32 lo = w << 16, hi = w & 0xffff0000u; float a, b;
    __builtin_memcpy(&a, &lo, 4); __builtin_memcpy(&b, &hi, 4);
    return make_float2(a, b);
}
template<bool F32> __device__ __forceinline__ float4 LD4(const void* p, int e) { // e%4==0
    if (F32) return ((const float4*)p)[e >> 2];
    uint2 w = ((const uint2*)p)[e >> 2];
    u32 a0 = w.x << 16, a1 = w.x & 0xffff0000u, a2 = w.y << 16, a3 = w.y & 0xffff0000u;
    float f0, f1, f2, f3;
    __builtin_memcpy(&f0, &a0, 4); __builtin_memcpy(&f1, &a1, 4);
    __builtin_memcpy(&f2, &a2, 4); __builtin_memcpy(&f3, &a3, 4);
    return make_float4(f0, f1, f2, f3);
}
template<bool F32> __device__ __forceinline__ void ST(void* p, int e, float v) {
    if (F32) ((float*)p)[e] = v; else ((u16*)p)[e] = f2bf(v);
}

struct Args {
    const void *form, *ctx;
    const void *mod_W, *mod_b, *wch_W, *wch_b, *wdl_W, *wdl_b, *wep_W, *wep_b;
    const void *vch_W, *vch_b, *vep_W, *vep_b;
    const void *wnc_W, *wnc_b, *wnd_W, *wnd_b, *wne_W, *wne_b;
    const void *m_W, *m_Wb, *mb_W, *mb_b;
    void* outp;
};

// dtype probe: block-uniform, deterministic. Returns 1 if inputs are fp32.
__device__ __forceinline__ int probe_is_f32(const void* ctx, int t, int* flag_s) {
    if (t == 0) {
        int sane = 0;
        const u16* q = (const u16*)ctx;
        for (int i = 0; i < 64; ++i) {
            u16 u = q[2 * i];
            int ex = (u >> 7) & 0xFF;
            sane += (u == 0 || (ex >= 112 && ex <= 143)) ? 1 : 0;
        }
        *flag_s = (sane < 32) ? 1 : 0;
    }
    __syncthreads();
    return *flag_s;
}

// hi/lo bf16 split (Markidis): x ~= hi + lo, |err| ~ 2^-18 |x|
__device__ __forceinline__ void split_bf16(float x, u16& hi, u16& lo) {
    hi = f2bf(x);
    lo = f2bf(x - bfu(hi));
}

// ============================================================================
// Y column map, n in [0,7168):
//  [0,1024) wch | [1024,2048) vch | [2048,4096) vepI (2048+2u+s <- vep 4u+2s)
//  [4096,7168) Wk (4096 + k*1024 + j <- m_W[k][.][j])
// ============================================================================

// ---------------- Kernel R1: pack W -> Bpack[T][h][kb][l][8] bf16 ----------
// B-frag for mfma_f32_16x16x32_bf16: lane l holds B[k][n], n = l&15,
// k = kb*32 + (l>>4)*8 + j. Packed so a frag load is one coalesced b128.
template<bool F32>
__device__ void packw_body(int g, const Args& A, u16* Bpack, float* bcat) {
    int l  = g & 63;
    int kb = (g >> 6) & 3;
    int h  = (g >> 8) & 1;
    int T  = g >> 9;                      // 0..447
    int n  = T * 16 + (l & 15);
    int k0 = kb * 32 + (l >> 4) * 8;

    const void* p; int off, st;
    if (n < 1024)      { p = A.wch_W; off = n;           st = 1024; }
    else if (n < 2048) { p = A.vch_W; off = n - 1024;    st = 1024; }
    else if (n < 4096) { int i = n - 2048; int col = 4 * (i >> 1) + 2 * (i & 1);
                         p = A.vep_W; off = col;         st = 4096; }
    else               { int i = n - 4096; int kk = i >> 10, j2 = i & 1023;
                         p = A.m_W;  off = kk * 131072 + j2; st = 1024; }

    u16 out[8];
    #pragma unroll
    for (int j = 0; j < 8; ++j) {
        float w = LD<F32>(p, off + (k0 + j) * st);
        u16 whi, wlo; split_bf16(w, whi, wlo);
        out[j] = h ? wlo : whi;
    }
    *(uint4*)(Bpack + (size_t)g * 8) = *(const uint4*)out;

    if (h == 0 && kb == 0 && l < 16) {    // 448*16 = 7168 bias entries
        float bb;
        if (n < 1024)      bb = LD<F32>(A.wch_b, n);
        else if (n < 2048) bb = LD<F32>(A.vch_b, n - 1024);
        else if (n < 4096) { int i = n - 2048; bb = LD<F32>(A.vep_b, 4 * (i >> 1) + 2 * (i & 1)); }
        else               { int i = n - 4096; bb = LD<F32>(A.m_Wb, (i >> 10) * 1024 + (i & 1023)); }
        bcat[n] = bb;
    }
}

__global__ __launch_bounds__(256) void packw_kernel(Args A, u16* Bpack, float* bcat) {
    __shared__ int dt_s;
    const int t = threadIdx.x;
    int isf32 = probe_is_f32(A.ctx, t, &dt_s);
    int g = blockIdx.x * 256 + t;         // 896 blocks -> 229376 = 448*2*4*64
    if (isf32) packw_body<true>(g, A, Bpack, bcat);
    else       packw_body<false>(g, A, Bpack, bcat);
}

// ---------------- Kernel R2: pack ctx -> Apack[M][h][kb][l][8] bf16 ---------
// A-frag: lane l holds A[m][k], m = l&15, k = kb*32 + (l>>4)*8 + j.
template<bool F32>
__device__ void packa_body(int g, const Args& A, u16* Apack) {
    int l  = g & 63;
    int kb = (g >> 6) & 3;
    int h  = (g >> 8) & 1;
    int M  = g >> 9;                      // 0..127
    int m  = M * 16 + (l & 15);
    int k0 = kb * 32 + (l >> 4) * 8;

    u16 out[8];
    float4 x = LD4<F32>(A.ctx, m * 128 + k0);
    float4 y = LD4<F32>(A.ctx, m * 128 + k0 + 4);
    float v[8] = {x.x, x.y, x.z, x.w, y.x, y.y, y.z, y.w};
    #pragma unroll
    for (int j = 0; j < 8; ++j) {
        u16 whi, wlo; split_bf16(v[j], whi, wlo);
        out[j] = h ? wlo : whi;
    }
    *(uint4*)(Apack + (size_t)g * 8) = *(const uint4*)out;
}

__global__ __launch_bounds__(256) void packa_kernel(Args A, u16* Apack) {
    __shared__ int dt_s;
    const int t = threadIdx.x;
    int isf32 = probe_is_f32(A.ctx, t, &dt_s);
    int g = blockIdx.x * 256 + t;         // 256 blocks -> 65536 = 128*2*4*64
    if (isf32) packa_body<true>(g, A, Apack);
    else       packa_body<false>(g, A, Apack);
}

// ---------------- Kernel G: MFMA GEMM  Y = ctx @ W + b (split-bf16 3-pass) --
// Grid 3584 = 28 nb x 128 Mt (consecutive blocks share the B 256-col range).
// Block = 4 waves; wave w computes n-tiles Tbase..Tbase+3 (64 cols), M-tile Mt.
// D = sum_kb [Ahi*Bhi + Ahi*Blo + Alo*Bhi]  (fp32 accumulate)
__global__ __launch_bounds__(256) void gemm_mfma_kernel(
    const u16* __restrict__ Apack, const u16* __restrict__ Bpack,
    const float* __restrict__ bcat, float* __restrict__ Y) {
    __shared__ __align__(16) u16 Astage[4096];    // one M-tile's pack (8 KB)

    const int t  = threadIdx.x;
    const int l  = t & 63;
    const int w  = t >> 6;
    const int Mt = blockIdx.x & 127;
    const int nb = blockIdx.x >> 7;

    // stage Apack[Mt] (512 uint4)
    {
        const uint4* Ap4 = (const uint4*)(Apack + (size_t)Mt * 4096);
        uint4* As4 = (uint4*)Astage;
        As4[t] = Ap4[t];
        As4[t + 256] = Ap4[t + 256];
    }
    __syncthreads();

    // A-frags from LDS (conflict-free b128)
    bf16x8 ahi[4], alo[4];
    #pragma unroll
    for (int kb = 0; kb < 4; ++kb) {
        ahi[kb] = *(const bf16x8*)(Astage + ((0 * 4 + kb) * 64 + l) * 8);
        alo[kb] = *(const bf16x8*)(Astage + ((1 * 4 + kb) * 64 + l) * 8);
    }

    const int Tbase = nb * 16 + w * 4;
    const int row0  = Mt * 16 + (l >> 4) * 4;
    const int ncol  = l & 15;

    #pragma unroll
    for (int T = 0; T < 4; ++T) {
        const u16* Bb = Bpack + (size_t)(Tbase + T) * 4096;
        bf16x8 bhi[4], blo[4];
        #pragma unroll
        for (int kb = 0; kb < 4; ++kb) {
            bhi[kb] = *(const bf16x8*)(Bb + ((0 * 4 + kb) * 64 + l) * 8);
            blo[kb] = *(const bf16x8*)(Bb + ((1 * 4 + kb) * 64 + l) * 8);
        }
        f32x4 d = {0.f, 0.f, 0.f, 0.f};
        #pragma unroll
        for (int kb = 0; kb < 4; ++kb) {
            d = __builtin_amdgcn_mfma_f32_16x16x32_bf16(ahi[kb], bhi[kb], d, 0, 0, 0);
            d = __builtin_amdgcn_mfma_f32_16x16x32_bf16(ahi[kb], blo[kb], d, 0, 0, 0);
            d = __builtin_amdgcn_mfma_f32_16x16x32_bf16(alo[kb], bhi[kb], d, 0, 0, 0);
        }
        int n = (Tbase + T) * 16 + ncol;
        float bv = bcat[n];
        #pragma unroll
        for (int i = 0; i < 4; ++i) {
            Y[(size_t)(row0 + i) * YS2 + n] = d[i] + bv;
        }
    }
}

// ============================================================================
// Kernel 2: smalls-from-ctx + match + xtab + parallel-gated scan (r7, proven)
// ============================================================================
struct __align__(16) ScanSmem {
    float U[6144];
    float V[3072];
    float match_s[512];
    float wnc_s[64];
    float wep0_s[16], wep2_s[16], wdl_s[16];
    float coef_s[96];
    float sc_s[2];
};

template<bool F32>
__device__ void scan_body(ScanSmem& S, int t, int b, const Args& A, const float* __restrict__ Y) {
    float* Wk_s   = S.U;
    float* bk_s   = S.U + 3072;
    float* modl   = S.U + 3120;
    float* form_s = S.U + 3312;
    float* ctx_s  = S.U + 5424;
    float* xtab   = S.U;
    float* wch_s  = S.V;
    float* vch_s  = S.V + 1024;
    float* rlI    = S.V + 2048;
    float* gtab   = S.V;

    const float* Yr = Y + (size_t)b * YS2;
    const float4* Y4 = (const float4*)Yr;

    const int f_own = t & 63;
    const int fq    = t >> 6;

    const float2* vep2p = (const float2*)(Yr + 2048);
    v2f vepf[16];
    #pragma unroll
    for (int p = 0; p < 16; ++p) {
        float2 v = vep2p[p * 64 + f_own];
        vepf[p].x = v.x; vepf[p].y = v.y;
    }

    {
        int e0 = b * 2048 + t * 8;
        float4 x = LD4<F32>(A.form, e0);
        float4 y = LD4<F32>(A.form, e0 + 4);
        int f = t >> 2, r0 = (t & 3) * 8;
        float* dst = form_s + f * 33 + r0;
        dst[0] = x.x; dst[1] = x.y; dst[2] = x.z; dst[3] = x.w;
        dst[4] = y.x; dst[5] = y.y; dst[6] = y.z; dst[7] = y.w;
    }
    if (t < 32) {
        float4 v = LD4<F32>(A.ctx, b * 128 + 4 * t);
        *(float4*)&ctx_s[4 * t] = v;
    }
    for (int i = t; i < 768; i += 256) ((float4*)Wk_s)[i] = Y4[1024 + i];
    ((float4*)wch_s)[t] = Y4[t];
    ((float4*)vch_s)[t] = Y4[256 + t];
    __syncthreads();

    if (t < 96) {
        float a = LD<F32>(A.mod_b, t);
        for (int c = 0; c < 128; ++c) a += ctx_s[c] * LD<F32>(A.mod_W, c * 96 + t);
        modl[t] = a;
    } else if (t < 144) {
        int i = t - 96; int k = i >> 4, p = i & 15;
        float a = LD<F32>(A.mb_b, k * 16 + p);
        for (int c = 0; c < 128; ++c) a += ctx_s[c] * LD<F32>(A.mb_W, (k * 128 + c) * 16 + p);
        bk_s[i] = a;
    } else if (t < 208) {
        int f = t - 144;
        float a = LD<F32>(A.wnc_b, f);
        for (int c = 0; c < 128; ++c) a += ctx_s[c] * LD<F32>(A.wnc_W, c * 64 + f);
        S.wnc_s[f] = __expf(a);
    } else if (t < 224) {
        int p = t - 208;
        float a0 = LD<F32>(A.wep_b, 4 * p), a2 = LD<F32>(A.wep_b, 4 * p + 2);
        for (int c = 0; c < 128; ++c) {
            float cv = ctx_s[c];
            a0 += cv * LD<F32>(A.wep_W, c * 64 + 4 * p);
            a2 += cv * LD<F32>(A.wep_W, c * 64 + 4 * p + 2);
        }
        S.wep0_s[p] = a0; S.wep2_s[p] = a2;
    } else if (t < 240) {
        int p = t - 224;
        float a = LD<F32>(A.wdl_b, p);
        for (int c = 0; c < 128; ++c) a += ctx_s[c] * LD<F32>(A.wdl_W, c * 16 + p);
        S.wdl_s[p] = a;
    } else if (t < 242) {
        const void* W  = (t == 240) ? A.wnd_W : A.wne_W;
        const void* bb = (t == 240) ? A.wnd_b : A.wne_b;
        float a = LD<F32>(bb, 0);
        for (int c = 0; c < 128; ++c) a += ctx_s[c] * LD<F32>(W, c);
        S.sc_s[t - 240] = __expf(a);
    }
    __syncthreads();

    if (t < 16) {
        float v[6]; float mx = -1e30f;
        #pragma unroll
        for (int j = 0; j < 6; ++j) { v[j] = modl[t * 6 + j]; mx = fmaxf(mx, v[j]); }
        float s = 0.f;
        #pragma unroll
        for (int j = 0; j < 6; ++j) { v[j] = __expf(v[j] - mx); s += v[j]; }
        float inv = 1.f / s;
        #pragma unroll
        for (int j = 0; j < 6; ++j) modl[t * 6 + j] = v[j] * inv;
    }
    __syncthreads();

    if (t < 16) {
        S.wep0_s[t] *= modl[t * 6 + 2];
        S.wep2_s[t] *= modl[t * 6 + 4];
        S.wdl_s[t]  *= modl[t * 6 + 1];
    }
    for (int i = t; i < 1024; i += 256) wch_s[i] *= modl[(i >> 6) * 6];

    const int my_r = t & 31;
    #pragma unroll 1
    for (int it = 0; it < 2; ++it) {
        int idx = t + 256 * it;
        int p = idx >> 5, r = idx & 31;
        float s0 = bk_s[p], s1 = bk_s[16 + p], s2 = bk_s[32 + p];
        const float4* w0 = (const float4*)(Wk_s + p * 64);
        const float4* w1 = (const float4*)(Wk_s + (16 + p) * 64);
        const float4* w2 = (const float4*)(Wk_s + (32 + p) * 64);
        for (int f4 = 0; f4 < 16; ++f4) {
            float a0[4], a1[4], a2[4];
            *(float4*)a0 = w0[f4]; *(float4*)a1 = w1[f4]; *(float4*)a2 = w2[f4];
            #pragma unroll
            for (int j = 0; j < 4; ++j) {
                int f = f4 * 4 + j;
                float f0 = form_s[f * 33 + r];
                float fm = __shfl_up(f0, 1, 32);   if (r == 0)  fm = 0.f;
                float fp = __shfl_down(f0, 1, 32); if (r == 31) fp = 0.f;
                s0 += a0[j] * fm; s1 += a1[j] * f0; s2 += a2[j] * fp;
            }
        }
        S.match_s[p * 32 + r] = __expf(lsg(s0) + lsg(s1) + lsg(s2));
    }
    __syncthreads();

    if (t < 96) {
        int sub = t >> 5, r = t & 31;
        const float* w = (sub == 0) ? S.wep0_s : (sub == 1) ? S.wdl_s : S.wep2_s;
        float s = 0.f;
        for (int p = 0; p < 16; ++p) s += S.match_s[p * 32 + r] * w[p];
        float cf;
        if (sub == 1) cf = 1.f - sigm(s - S.sc_s[0]);
        else          cf = sigm(s - S.sc_s[1]);
        S.coef_s[sub * 32 + r] = cf;
    }
    for (int i = t; i < 512; i += 256) {
        int p = i >> 5, r = i & 31;
        float m = S.match_s[p * 32 + r];
        rlI[2 * i]     = fmaxf(m * S.wep0_s[p], 0.f);
        rlI[2 * i + 1] = fmaxf(m * S.wep2_s[p], 0.f);
    }
    float wchf[16], vchf[16];
    #pragma unroll
    for (int p = 0; p < 16; ++p) {
        wchf[p] = wch_s[p * 64 + f_own];
        vchf[p] = vch_s[p * 64 + f_own];
    }
    const float wncf = S.wnc_s[f_own];
    float si_r[8];
    #pragma unroll
    for (int j = 0; j < 8; ++j) si_r[j] = form_s[f_own * 33 + fq * 8 + j];
    __syncthreads();

    #pragma unroll 1
    for (int j = 0; j < 8; ++j) {
        int rs = fq * 8 + j;
        v2f v02; v02.x = 0.f; v02.y = 0.f;
        float sum = 0.f, vs1 = 0.f;
        const v2f* rlp = (const v2f*)(rlI + 2 * rs);
        #pragma unroll
        for (int p = 0; p < 16; ++p) {
            v2f rl = rlp[p * 32];
            v02 += rl * vepf[p];
            float m = S.match_s[p * 32 + rs];
            float wc = m * wchf[p];
            sum += wc;
            vs1 += fmaxf(wc, 0.f) * vchf[p];
        }
        float pch = sigm(sum - wncf);
        float si  = si_r[j];
        xtab[0 * 2048 + rs * 64 + f_own] = v02.x;
        xtab[1 * 2048 + rs * 64 + f_own] = si + pch * (vs1 - si);
        xtab[2 * 2048 + rs * 64 + f_own] = v02.y;
    }
    __syncthreads();

    float* ck_s  = S.match_s;
    float* pos_s = S.match_s + 128;
    if (t < 96) ck_s[t] = S.coef_s[(t % 3) * 32 + (t / 3)];
    __syncthreads();
    if (t < 64) {
        float a = ck_s[t];
        float a0 = a;
        #pragma unroll
        for (int d = 1; d < 64; d <<= 1) { float v = __shfl_up(a, d, 64); if (t >= d) a += v; }
        pos_s[t] = a - a0;
        float carry = __shfl(a, 63, 64);
        float b2 = (t < 32) ? ck_s[64 + t] : 0.f;
        float c2 = b2;
        #pragma unroll
        for (int d = 1; d < 32; d <<= 1) { float v = __shfl_up(c2, d, 32); if ((t & 31) >= d) c2 += v; }
        if (t < 32) pos_s[64 + t] = carry + c2 - b2;
    }
    __syncthreads();

    #pragma unroll 1
    for (int i = 0; i < 12; ++i) {
        int idx = t + 256 * i;
        int k = idx >> 5, r = idx & 31;
        float posn = pos_s[k];
        float pc = fminf(posn, 31.f);
        float ci = floorf(pc + 0.5f);
        float dmin = posn - ci;
        float dd = posn - (float)r;
        float eo = __expf(-2.f * (dd * dd - dmin * dmin));
        float Z = eo;
        Z += __shfl_xor(Z, 1, 32);
        Z += __shfl_xor(Z, 2, 32);
        Z += __shfl_xor(Z, 4, 32);
        Z += __shfl_xor(Z, 8, 32);
        Z += __shfl_xor(Z, 16, 32);
        gtab[idx] = ck_s[k] * eo / Z;
    }
    __syncthreads();

    const int fgrp = t >> 5;
    v2f o01, o23, o45, o67;
    o01 = 0.f; o23 = 0.f; o45 = 0.f; o67 = 0.f;
    #pragma unroll 1
    for (int rs = 0; rs < 32; ++rs) {
        #pragma unroll
        for (int sub = 0; sub < 3; ++sub) {
            float g = gtab[(rs * 3 + sub) * 32 + my_r];
            v2f gv; gv.x = g; gv.y = g;
            const float4* xb = (const float4*)(xtab + sub * 2048 + rs * 64 + fgrp * 8);
            float4 xa = xb[0], xc = xb[1];
            v2f x01, x23, x45, x67;
            x01.x = xa.x; x01.y = xa.y; x23.x = xa.z; x23.y = xa.w;
            x45.x = xc.x; x45.y = xc.y; x67.x = xc.z; x67.y = xc.w;
            o01 += gv * (x01 - o01);
            o23 += gv * (x23 - o23);
            o45 += gv * (x45 - o45);
            o67 += gv * (x67 - o67);
        }
    }

    float oreg[8] = {o01.x, o01.y, o23.x, o23.y, o45.x, o45.y, o67.x, o67.y};
    #pragma unroll
    for (int i = 0; i < 8; ++i) {
        ST<F32>(A.outp, b * 2048 + (fgrp * 8 + i) * 32 + my_r, oreg[i]);
    }
}

__global__ __launch_bounds__(256) void scan_kernel(Args A, const float* Y) {
    __shared__ ScanSmem S;
    __shared__ int dt_s;
    const int t = threadIdx.x, b = blockIdx.x;
    int isf32 = probe_is_f32(A.ctx, t, &dt_s);
    if (isf32) scan_body<true>(S, t, b, A, Y);
    else       scan_body<false>(S, t, b, A, Y);
}

// ---------------- Last-resort monolithic fallback (round-2, proven) ---------
struct Smem {
    float U[6144];
    float form_s[64 * 33];
    float match_s[512];
    float wch_s[1024];
    float vch_s[1024];
    float vep0_s[1024];
    float vep2_s[1024];
    float wep0_s[16], wep2_s[16], wdl_s[16];
    float wnc_s[64];
    float sc_s[2];
    float ssum_s[96];
};

template<bool F32>
__device__ void mono_body(Smem& S, int t, int b, const Args& A) {
    float* c_s  = S.U;
    float* modl = S.U + 128;
    float* Wk_s = S.U + 224;
    float* bk_s = S.U + 3344;
    float* xtab = S.U;

    if (t < 128) c_s[t] = LD<F32>(A.ctx, b * 128 + t);
    {
        int e0 = b * 2048 + t * 8;
        float4 x = LD4<F32>(A.form, e0);
        float4 y = LD4<F32>(A.form, e0 + 4);
        int f = t >> 2, r0 = (t & 3) * 8;
        float* dst = S.form_s + f * 33 + r0;
        dst[0] = x.x; dst[1] = x.y; dst[2] = x.z; dst[3] = x.w;
        dst[4] = y.x; dst[5] = y.y; dst[6] = y.z; dst[7] = y.w;
    }
    __syncthreads();
    if (t < 96) {
        float a = LD<F32>(A.mod_b, t);
        for (int cc = 0; cc < 128; ++cc) a += c_s[cc] * LD<F32>(A.mod_W, cc * 96 + t);
        modl[t] = a;
    }
    __syncthreads();
    if (t < 16) {
        float v[6]; float mx = -1e30f;
        #pragma unroll
        for (int j = 0; j < 6; ++j) { v[j] = modl[t * 6 + j]; mx = fmaxf(mx, v[j]); }
        float s = 0.f;
        #pragma unroll
        for (int j = 0; j < 6; ++j) { v[j] = __expf(v[j] - mx); s += v[j]; }
        float inv = 1.f / s;
        #pragma unroll
        for (int j = 0; j < 6; ++j) modl[t * 6 + j] = v[j] * inv;
    }
    __syncthreads();
    for (int j = t; j < 512; j += 256) {
        int n0 = j * 2;
        float2 bb = LD2<F32>(A.wch_b, n0);
        float a0 = bb.x, a1 = bb.y;
        for (int cc = 0; cc < 128; ++cc) {
            float2 w = LD2<F32>(A.wch_W, cc * 1024 + n0); float cv = c_s[cc];
            a0 += cv * w.x; a1 += cv * w.y;
        }
        int p = n0 >> 6; float sc = modl[p * 6 + 0];
        S.wch_s[n0] = sc * a0; S.wch_s[n0 + 1] = sc * a1;
    }
    for (int j = t; j < 512; j += 256) {
        int n0 = j * 2;
        float2 bb = LD2<F32>(A.vch_b, n0);
        float a0 = bb.x, a1 = bb.y;
        for (int cc = 0; cc < 128; ++cc) {
            float2 w = LD2<F32>(A.vch_W, cc * 1024 + n0); float cv = c_s[cc];
            a0 += cv * w.x; a1 += cv * w.y;
        }
        S.vch_s[n0] = a0; S.vch_s[n0 + 1] = a1;
    }
    for (int u = t; u < 1024; u += 256) {
        int n0 = u * 4;
        float4 bb = LD4<F32>(A.vep_b, n0);
        float a0 = bb.x, a2 = bb.z;
        for (int cc = 0; cc < 128; ++cc) {
            float4 w = LD4<F32>(A.vep_W, cc * 4096 + n0); float cv = c_s[cc];
            a0 += cv * w.x; a2 += cv * w.z;
        }
        S.vep0_s[u] = a0; S.vep2_s[u] = a2;
    }
    for (int j = t; j < 1536; j += 256) {
        int k  = j >> 9;
        int jj = j & 511;
        int n0 = jj * 2;
        float2 bb = LD2<F32>(A.m_Wb, k * 1024 + n0);
        float a0 = bb.x, a1 = bb.y;
        for (int cc = 0; cc < 128; ++cc) {
            float2 w = LD2<F32>(A.m_W, (k * 128 + cc) * 1024 + n0); float cv = c_s[cc];
            a0 += cv * w.x; a1 += cv * w.y;
        }
        int p = n0 >> 6, f = n0 & 63;
        Wk_s[(k * 16 + p) * 65 + f]     = a0;
        Wk_s[(k * 16 + p) * 65 + f + 1] = a1;
    }
    if (t < 16) {
        int n0 = t * 4;
        float4 bb = LD4<F32>(A.wep_b, n0);
        float a0 = bb.x, a2 = bb.z;
        for (int cc = 0; cc < 128; ++cc) {
            float4 w = LD4<F32>(A.wep_W, cc * 64 + n0); float cv = c_s[cc];
            a0 += cv * w.x; a2 += cv * w.z;
        }
        S.wep0_s[t] = modl[t * 6 + 2] * a0;
        S.wep2_s[t] = modl[t * 6 + 4] * a2;
    } else if (t < 32) {
        int p = t - 16;
        float a = LD<F32>(A.wdl_b, p);
        for (int cc = 0; cc < 128; ++cc) a += c_s[cc] * LD<F32>(A.wdl_W, cc * 16 + p);
        S.wdl_s[p] = modl[p * 6 + 1] * a;
    } else if (t < 96) {
        int f = t - 32;
        float a = LD<F32>(A.wnc_b, f);
        for (int cc = 0; cc < 128; ++cc) a += c_s[cc] * LD<F32>(A.wnc_W, cc * 64 + f);
        S.wnc_s[f] = __expf(a);
    } else if (t < 98) {
        const void* W  = (t == 96) ? A.wnd_W : A.wne_W;
        const void* bb = (t == 96) ? A.wnd_b : A.wne_b;
        float a = LD<F32>(bb, 0);
        for (int cc = 0; cc < 128; ++cc) a += c_s[cc] * LD<F32>(W, cc);
        S.sc_s[t - 96] = __expf(a);
    } else if (t < 146) {
        int i = t - 98;
        int k = i >> 4, p = i & 15;
        float a = LD<F32>(A.mb_b, k * 16 + p);
        for (int cc = 0; cc < 128; ++cc) a += c_s[cc] * LD<F32>(A.mb_W, (k * 128 + cc) * 16 + p);
        bk_s[i] = a;
    }
    __syncthreads();
    for (int idx = t; idx < 512; idx += 256) {
        int p = idx >> 5, r = idx & 31;
        float s0 = bk_s[p], s1 = bk_s[16 + p], s2 = bk_s[32 + p];
        const float* w0 = Wk_s + p * 65;
        const float* w1 = Wk_s + (16 + p) * 65;
        const float* w2 = Wk_s + (32 + p) * 65;
        for (int f = 0; f < 64; ++f) {
            const float* fr = S.form_s + f * 33 + r;
            float fm1 = (r > 0)  ? fr[-1] : 0.f;
            float f0  = fr[0];
            float fp1 = (r < 31) ? fr[1]  : 0.f;
            s0 += w0[f] * fm1; s1 += w1[f] * f0; s2 += w2[f] * fp1;
        }
        S.match_s[p * 32 + r] = __expf(lsg(s0) + lsg(s1) + lsg(s2));
    }
    __syncthreads();
    if (t < 96) {
        int which = t >> 5, r = t & 31;
        const float* w = (which == 0) ? S.wep0_s : (which == 1) ? S.wep2_s : S.wdl_s;
        float s = 0.f;
        for (int p = 0; p < 16; ++p) s += S.match_s[p * 32 + r] * w[p];
        S.ssum_s[which * 32 + r] = s;
    }
    #pragma unroll 1
    for (int q = 0; q < 24; ++q) {
        int idx = t + 256 * q;
        int sub = idx >> 11;
        int rs  = (idx >> 6) & 31;
        int f   = idx & 63;
        float x;
        if (sub == 1) {
            float sum = 0.f, vs = 0.f;
            for (int p = 0; p < 16; ++p) {
                float wc = S.match_s[p * 32 + rs] * S.wch_s[p * 64 + f];
                sum += wc;
                vs  += fmaxf(wc, 0.f) * S.vch_s[p * 64 + f];
            }
            float pch = sigm(sum - S.wnc_s[f]);
            float si  = S.form_s[f * 33 + rs];
            x = si + pch * (vs - si);
        } else {
            const float* wep = (sub == 0) ? S.wep0_s : S.wep2_s;
            const float* vep = (sub == 0) ? S.vep0_s : S.vep2_s;
            float vs = 0.f;
            for (int p = 0; p < 16; ++p) {
                float w = S.match_s[p * 32 + rs] * wep[p];
                vs += fmaxf(w, 0.f) * vep[p * 64 + f];
            }
            x = vs;
        }
        xtab[idx] = x;
    }
    __syncthreads();
    const int my_r = t & 31;
    const int fgrp = t >> 5;
    float oreg[8];
    #pragma unroll
    for (int i = 0; i < 8; ++i) oreg[i] = 0.f;
    float posn = 0.f;
    const float wnd1v = S.sc_s[0];
    const float wne1v = S.sc_s[1];
    for (int rs = 0; rs < 32; ++rs) {
        #pragma unroll
        for (int sub = 0; sub < 3; ++sub) {
            float coef;
            if (sub == 1) coef = 1.f - sigm(S.ssum_s[64 + rs] - wnd1v);
            else          coef = sigm(S.ssum_s[(sub & 2) * 16 + rs] - wne1v);
            float pc = fminf(posn, 31.f);
            int ci = (int)(pc + 0.5f);
            int lo = ci - 4; if (lo < 0)  lo = 0;
            int hi = ci + 4; if (hi > 31) hi = 31;
            float dmin = posn - (float)ci;
            float mx = -2.f * dmin * dmin;
            float Z = 0.f, eo = 0.f;
            for (int r = lo; r <= hi; ++r) {
                float d = posn - (float)r;
                float e = __expf(-2.f * d * d - mx);
                Z += e;
                if (r == my_r) eo = e;
            }
            float g = coef * eo / Z;
            const float* xb = xtab + (sub * 2048 + rs * 64 + fgrp * 8);
            #pragma unroll
            for (int i = 0; i < 8; ++i) oreg[i] += g * (xb[i] - oreg[i]);
            posn += coef;
        }
    }
    #pragma unroll
    for (int i = 0; i < 8; ++i) {
        ST<F32>(A.outp, b * 2048 + (fgrp * 8 + i) * 32 + my_r, oreg[i]);
    }
}

__global__ __launch_bounds__(256) void phon_mono(Args A) {
    __shared__ Smem S;
    __shared__ int dt_s;
    const int t = threadIdx.x, b = blockIdx.x;
    int isf32 = probe_is_f32(A.ctx, t, &dt_s);
    if (isf32) mono_body<true>(S, t, b, A);
    else       mono_body<false>(S, t, b, A);
}

extern "C" void kernel_launch(void* const* d_in, const int* in_sizes, int n_in,
                              void* d_out, int out_size, void* d_ws, size_t ws_size,
                              hipStream_t stream) {
    Args A;
    A.form  = d_in[0];  A.ctx   = d_in[1];
    A.mod_W = d_in[2];  A.mod_b = d_in[3];
    A.wch_W = d_in[4];  A.wch_b = d_in[5];
    A.wdl_W = d_in[6];  A.wdl_b = d_in[7];
    A.wep_W = d_in[8];  A.wep_b = d_in[9];
    A.vch_W = d_in[10]; A.vch_b = d_in[11];
    A.vep_W = d_in[12]; A.vep_b = d_in[13];
    A.wnc_W = d_in[14]; A.wnc_b = d_in[15];
    A.wnd_W = d_in[16]; A.wnd_b = d_in[17];
    A.wne_W = d_in[18]; A.wne_b = d_in[19];
    A.m_W   = d_in[20]; A.m_Wb  = d_in[21];
    A.mb_W  = d_in[22]; A.mb_b  = d_in[23];
    A.outp  = d_out;

    const size_t yElems  = (size_t)B_ * YS2;            // 14,680,064 f32
    const size_t bpElems = (size_t)NTILES * 4096;       // u16
    const size_t apElems = (size_t)128 * 4096;          // u16
    const size_t need = yElems * 4 + (bpElems + apElems) * 2 + YS2 * 4;
    if (ws_size >= need) {
        float* Y     = (float*)d_ws;
        u16*   Bpack = (u16*)(Y + yElems);
        u16*   Apack = Bpack + bpElems;
        float* bcat  = (float*)(Apack + apElems);
        packw_kernel<<<896, 256, 0, stream>>>(A, Bpack, bcat);
        packa_kernel<<<256, 256, 0, stream>>>(A, Apack);
        gemm_mfma_kernel<<<3584, 256, 0, stream>>>(Apack, Bpack, bcat, Y);
        scan_kernel<<<B_, 256, 0, stream>>>(A, Y);
    } else {
        phon_mono<<<B_, 256, 0, stream>>>(A);
    }
}

// Round 9
// 243.805 us; speedup vs baseline: 1.9332x; 1.0905x over previous
//
#include <hip/hip_runtime.h>

// Problem constants: B=2048, F=64, R=32, P=16, C=128, TAU=2.0
#define B_ 2048
#define YS3 7440   // Y stride = 465 tiles x 16
#define NT  465

typedef unsigned short u16;
typedef unsigned int   u32;
typedef __attribute__((ext_vector_type(2))) float v2f;
typedef __attribute__((ext_vector_type(8))) short bf16x8;  // 8 bf16 = 4 VGPR
typedef __attribute__((ext_vector_type(4))) float f32x4;

__device__ __forceinline__ float bfu(u16 u) {
    u32 i = ((u32)u) << 16; float f; __builtin_memcpy(&f, &i, 4); return f;
}
__device__ __forceinline__ u16 f2bf(float v) {
    u32 iv; __builtin_memcpy(&iv, &v, 4);
    u32 r = (iv + 0x7fffu + ((iv >> 16) & 1u)) >> 16;
    return (u16)r;
}
__device__ __forceinline__ float sigm(float x) { return 1.f / (1.f + __expf(-x)); }
__device__ __forceinline__ float lsg(float x) {
    return fminf(x, 0.f) - log1pf(__expf(-fabsf(x)));
}

template<bool F32> __device__ __forceinline__ float LD(const void* p, int e) {
    if (F32) return ((const float*)p)[e];
    return bfu(((const u16*)p)[e]);
}
template<bool F32> __device__ __forceinline__ float2 LD2(const void* p, int e) { // e even
    if (F32) { const float* q = (const float*)p; return make_float2(q[e], q[e + 1]); }
    u32 w = ((const u32*)p)[e >> 1];
    u32 lo = w << 16, hi = w & 0xffff0000u; float a, b;
    __builtin_memcpy(&a, &lo, 4); __builtin_memcpy(&b, &hi, 4);
    return make_float2(a, b);
}
template<bool F32> __device__ __forceinline__ float4 LD4(const void* p, int e) { // e%4==0
    if (F32) return ((const float4*)p)[e >> 2];
    uint2 w = ((const uint2*)p)[e >> 2];
    u32 a0 = w.x << 16, a1 = w.x & 0xffff0000u, a2 = w.y << 16, a3 = w.y & 0xffff0000u;
    float f0, f1, f2, f3;
    __builtin_memcpy(&f0, &a0, 4); __builtin_memcpy(&f1, &a1, 4);
    __builtin_memcpy(&f2, &a2, 4); __builtin_memcpy(&f3, &a3, 4);
    return make_float4(f0, f1, f2, f3);
}
template<bool F32> __device__ __forceinline__ void ST(void* p, int e, float v) {
    if (F32) ((float*)p)[e] = v; else ((u16*)p)[e] = f2bf(v);
}

struct Args {
    const void *form, *ctx;
    const void *mod_W, *mod_b, *wch_W, *wch_b, *wdl_W, *wdl_b, *wep_W, *wep_b;
    const void *vch_W, *vch_b, *vep_W, *vep_b;
    const void *wnc_W, *wnc_b, *wnd_W, *wnd_b, *wne_W, *wne_b;
    const void *m_W, *m_Wb, *mb_W, *mb_b;
    void* outp;
};

// dtype probe: block-uniform, deterministic. Returns 1 if inputs are fp32.
__device__ __forceinline__ int probe_is_f32(const void* ctx, int t, int* flag_s) {
    if (t == 0) {
        int sane = 0;
        const u16* q = (const u16*)ctx;
        for (int i = 0; i < 64; ++i) {
            u16 u = q[2 * i];
            int ex = (u >> 7) & 0xFF;
            sane += (u == 0 || (ex >= 112 && ex <= 143)) ? 1 : 0;
        }
        *flag_s = (sane < 32) ? 1 : 0;
    }
    __syncthreads();
    return *flag_s;
}

// hi/lo bf16 split (Markidis): x ~= hi + lo, |err| ~ 2^-18 |x|
__device__ __forceinline__ void split_bf16(float x, u16& hi, u16& lo) {
    hi = f2bf(x);
    lo = f2bf(x - bfu(hi));
}

// ============================================================================
// Y column map, n in [0,7440):
//  [0,1024) wch | [1024,2048) vch | [2048,4096) vepI (2048+2u+s <- vep 4u+2s)
//  [4096,7168) Wk (4096+k*1024+j <- m_W[k][.][j]) | [7168,7264) mod
//  [7264,7312) bk (k*16+p <- mb_W) | [7312,7344) wepI (7312+2u+s <- wep 4u+2s)
//  [7344,7360) wdl | [7360,7424) wnc | [7424] wnd | [7425] wne | [7426,7440) 0
// ============================================================================

// ---------------- Kernel R1: pack W -> Bpack[T][h][kb][l][8] bf16 -----------
// B-frag for mfma_f32_16x16x32_bf16: lane l holds B[k][n], n = l&15,
// k = kb*32 + (l>>4)*8 + j. Merged hi/lo: one thread writes both planes.
template<bool F32>
__device__ void packw_body(int g, const Args& A, u16* Bpack, float* bcat) {
    int l  = g & 63;
    int kb = (g >> 6) & 3;
    int T  = g >> 8;                      // 0..464
    int n  = T * 16 + (l & 15);
    int k0 = kb * 32 + (l >> 4) * 8;

    const void* p = A.wch_W; int off = 0, st = 0, zero = 0; float bb = 0.f;
    if (n < 1024)      { off = n; st = 1024; bb = LD<F32>(A.wch_b, n); }
    else if (n < 2048) { int j = n - 1024; p = A.vch_W; off = j; st = 1024; bb = LD<F32>(A.vch_b, j); }
    else if (n < 4096) { int i = n - 2048; int col = 4 * (i >> 1) + 2 * (i & 1);
                         p = A.vep_W; off = col; st = 4096; bb = LD<F32>(A.vep_b, col); }
    else if (n < 7168) { int i = n - 4096; int kk = i >> 10, j = i & 1023;
                         p = A.m_W; off = kk * 131072 + j; st = 1024; bb = LD<F32>(A.m_Wb, kk * 1024 + j); }
    else if (n < 7264) { int m = n - 7168; p = A.mod_W; off = m; st = 96; bb = LD<F32>(A.mod_b, m); }
    else if (n < 7312) { int i = n - 7264; int k = i >> 4, pp = i & 15;
                         p = A.mb_W; off = k * 2048 + pp; st = 16; bb = LD<F32>(A.mb_b, k * 16 + pp); }
    else if (n < 7344) { int i = n - 7312; int col = 4 * (i >> 1) + 2 * (i & 1);
                         p = A.wep_W; off = col; st = 64; bb = LD<F32>(A.wep_b, col); }
    else if (n < 7360) { int j = n - 7344; p = A.wdl_W; off = j; st = 16; bb = LD<F32>(A.wdl_b, j); }
    else if (n < 7424) { int j = n - 7360; p = A.wnc_W; off = j; st = 64; bb = LD<F32>(A.wnc_b, j); }
    else if (n == 7424){ p = A.wnd_W; off = 0; st = 1; bb = LD<F32>(A.wnd_b, 0); }
    else if (n == 7425){ p = A.wne_W; off = 0; st = 1; bb = LD<F32>(A.wne_b, 0); }
    else zero = 1;

    u16 hi[8], lo[8];
    #pragma unroll
    for (int j = 0; j < 8; ++j) {
        float w = LD<F32>(p, off + (k0 + j) * st);
        if (zero) w = 0.f;
        split_bf16(w, hi[j], lo[j]);
    }
    *(uint4*)(Bpack + ((size_t)T * 512 + kb * 64 + l) * 8)       = *(const uint4*)hi;
    *(uint4*)(Bpack + ((size_t)T * 512 + 256 + kb * 64 + l) * 8) = *(const uint4*)lo;
    if (kb == 0 && l < 16) bcat[n] = zero ? 0.f : bb;
}

__global__ __launch_bounds__(256) void packw_kernel(Args A, u16* Bpack, float* bcat) {
    __shared__ int dt_s;
    const int t = threadIdx.x;
    int isf32 = probe_is_f32(A.ctx, t, &dt_s);
    int g = blockIdx.x * 256 + t;         // 465 blocks -> 119040 = 465*4*64
    if (isf32) packw_body<true>(g, A, Bpack, bcat);
    else       packw_body<false>(g, A, Bpack, bcat);
}

// ---------------- Kernel G: MFMA GEMM  Y = ctx @ W + b (split-bf16 3-pass) --
// Grid 3840 = 30 nb x 128 Mt (Mt fastest -> 128 consecutive blocks share B).
// Block: stage ctx rows [16][128] fp32 (pitch 132), split to hi/lo in-register.
// Wave w: n-tiles Tbase..Tbase+3 (guarded at NT=465).
template<bool F32>
__device__ void gemm_mfma_body(float* As, int t, int blk, const void* __restrict__ ctx,
                               const u16* __restrict__ Bpack,
                               const float* __restrict__ bcat, float* __restrict__ Y) {
    const int l  = t & 63;
    const int w  = t >> 6;
    const int Mt = blk & 127;
    const int nb = blk >> 7;

    {
        int row = t >> 4, c0 = (t & 15) * 8;
        float4 x = LD4<F32>(ctx, (Mt * 16 + row) * 128 + c0);
        float4 y = LD4<F32>(ctx, (Mt * 16 + row) * 128 + c0 + 4);
        *(float4*)&As[row * 132 + c0]     = x;
        *(float4*)&As[row * 132 + c0 + 4] = y;
    }
    __syncthreads();

    bf16x8 ahi[4], alo[4];
    const int m = l & 15;
    #pragma unroll
    for (int kb = 0; kb < 4; ++kb) {
        int k0 = kb * 32 + (l >> 4) * 8;
        const float* ap = &As[m * 132 + k0];
        #pragma unroll
        for (int j = 0; j < 8; ++j) {
            u16 hi, lo; split_bf16(ap[j], hi, lo);
            ahi[kb][j] = (short)hi;
            alo[kb][j] = (short)lo;
        }
    }

    const int Tbase = nb * 16 + w * 4;
    const int row0  = Mt * 16 + (l >> 4) * 4;
    const int ncol  = l & 15;

    #pragma unroll
    for (int T = 0; T < 4; ++T) {
        int Tt = Tbase + T;
        if (Tt >= NT) break;              // wave-uniform tail guard
        const u16* Bb = Bpack + (size_t)Tt * 4096;
        bf16x8 bhi[4], blo[4];
        #pragma unroll
        for (int kb = 0; kb < 4; ++kb) {
            bhi[kb] = *(const bf16x8*)(Bb + ((kb) * 64 + l) * 8);
            blo[kb] = *(const bf16x8*)(Bb + ((4 + kb) * 64 + l) * 8);
        }
        f32x4 d = {0.f, 0.f, 0.f, 0.f};
        #pragma unroll
        for (int kb = 0; kb < 4; ++kb) {
            d = __builtin_amdgcn_mfma_f32_16x16x32_bf16(ahi[kb], bhi[kb], d, 0, 0, 0);
            d = __builtin_amdgcn_mfma_f32_16x16x32_bf16(ahi[kb], blo[kb], d, 0, 0, 0);
            d = __builtin_amdgcn_mfma_f32_16x16x32_bf16(alo[kb], bhi[kb], d, 0, 0, 0);
        }
        int n = Tt * 16 + ncol;
        float bv = bcat[n];
        #pragma unroll
        for (int i = 0; i < 4; ++i) {
            Y[(size_t)(row0 + i) * YS3 + n] = d[i] + bv;
        }
    }
}

__global__ __launch_bounds__(256) void gemm_mfma_kernel(Args A, const u16* Bpack,
                                                        const float* bcat, float* Y) {
    __shared__ float As[16 * 132];
    __shared__ int dt_s;
    const int t = threadIdx.x, blk = blockIdx.x;
    int isf32 = probe_is_f32(A.ctx, t, &dt_s);
    if (isf32) gemm_mfma_body<true>(As, t, blk, A.ctx, Bpack, bcat, Y);
    else       gemm_mfma_body<false>(As, t, blk, A.ctx, Bpack, bcat, Y);
}

// ============================================================================
// Kernel 2: match + xtab + parallel-gated scan (r6 structure, Y-resident smalls)
// LDS (~39.9 KB -> 4 blocks/CU):
//   U[6144]: Wk@0(3072,p64) bk@3072(48) modl@3120(96) form@3312(2112,p33)
//            -> after match phase, U overlaid by xtab[6144]
//   V[3072]: wch@0(1024) vch@1024(1024) rlI@2048(1024) -> gtab[3072] in D
// ============================================================================
struct __align__(16) ScanSmem {
    float U[6144];
    float V[3072];
    float match_s[512];     // [p][r]; later ck@0(96) pos@128(96)
    float wnc_s[64];
    float wep0_s[16], wep2_s[16], wdl_s[16];
    float coef_s[96];       // [sub][rs] (sub 0:ep0, 1:deln, 2:ep2)
    float sc_s[2];          // {w_nodeln, w_noepen}
};

template<bool F32>
__device__ void scan_body(ScanSmem& S, int t, int b, const Args& A, const float* __restrict__ Y) {
    float* Wk_s   = S.U;
    float* bk_s   = S.U + 3072;
    float* modl   = S.U + 3120;
    float* form_s = S.U + 3312;    // pitch 33, 2112 floats
    float* xtab   = S.U;           // overlay after match phase
    float* wch_s  = S.V;
    float* vch_s  = S.V + 1024;
    float* rlI    = S.V + 2048;    // relu(match*wep) pairs
    float* gtab   = S.V;           // overlay in phase D

    const float* Yr = Y + (size_t)b * YS3;
    const float4* Y4 = (const float4*)Yr;

    const int f_own = t & 63;
    const int fq    = t >> 6;

    // ---- register-cache vep pairs straight from global Y (coalesced b64) ---
    const float2* vep2p = (const float2*)(Yr + 2048);
    v2f vepf[16];
    #pragma unroll
    for (int p = 0; p < 16; ++p) {
        float2 v = vep2p[p * 64 + f_own];
        vepf[p].x = v.x; vepf[p].y = v.y;
    }

    // ---- stage form + Y segments into LDS ----
    {
        int e0 = b * 2048 + t * 8;
        float4 x = LD4<F32>(A.form, e0);
        float4 y = LD4<F32>(A.form, e0 + 4);
        int f = t >> 2, r0 = (t & 3) * 8;
        float* dst = form_s + f * 33 + r0;
        dst[0] = x.x; dst[1] = x.y; dst[2] = x.z; dst[3] = x.w;
        dst[4] = y.x; dst[5] = y.y; dst[6] = y.z; dst[7] = y.w;
    }
    for (int i = t; i < 768; i += 256) ((float4*)Wk_s)[i] = Y4[1024 + i];    // Wk @4096
    if (t < 12) ((float4*)bk_s)[t] = Y4[1816 + t];                           // bk @7264
    if (t < 24) ((float4*)modl)[t] = Y4[1792 + t];                           // mod @7168
    ((float4*)wch_s)[t] = Y4[t];                                             // wch @0
    ((float4*)vch_s)[t] = Y4[256 + t];                                       // vch @1024
    if (t < 16) {
        S.wep0_s[t] = Yr[7312 + 2 * t];
        S.wep2_s[t] = Yr[7312 + 2 * t + 1];
        S.wdl_s[t]  = Yr[7344 + t];
    } else if (t >= 32 && t < 96) {
        S.wnc_s[t - 32] = __expf(Yr[7360 + (t - 32)]);
    } else if (t >= 96 && t < 98) {
        S.sc_s[t - 96] = __expf(Yr[7424 + (t - 96)]);
    }
    __syncthreads();

    // ---- softmax(6) on mod ----
    if (t < 16) {
        float v[6]; float mx = -1e30f;
        #pragma unroll
        for (int j = 0; j < 6; ++j) { v[j] = modl[t * 6 + j]; mx = fmaxf(mx, v[j]); }
        float s = 0.f;
        #pragma unroll
        for (int j = 0; j < 6; ++j) { v[j] = __expf(v[j] - mx); s += v[j]; }
        float inv = 1.f / s;
        #pragma unroll
        for (int j = 0; j < 6; ++j) modl[t * 6 + j] = v[j] * inv;
    }
    __syncthreads();

    // ---- mod scaling + phase C (match) ----
    if (t < 16) {
        S.wep0_s[t] *= modl[t * 6 + 2];
        S.wep2_s[t] *= modl[t * 6 + 4];
        S.wdl_s[t]  *= modl[t * 6 + 1];
    }
    for (int i = t; i < 1024; i += 256) wch_s[i] *= modl[(i >> 6) * 6];

    const int my_r = t & 31;
    #pragma unroll 1
    for (int it = 0; it < 2; ++it) {
        int idx = t + 256 * it;
        int p = idx >> 5, r = idx & 31;
        float s0 = bk_s[p], s1 = bk_s[16 + p], s2 = bk_s[32 + p];
        const float4* w0 = (const float4*)(Wk_s + p * 64);
        const float4* w1 = (const float4*)(Wk_s + (16 + p) * 64);
        const float4* w2 = (const float4*)(Wk_s + (32 + p) * 64);
        for (int f4 = 0; f4 < 16; ++f4) {
            float a0[4], a1[4], a2[4];
            *(float4*)a0 = w0[f4]; *(float4*)a1 = w1[f4]; *(float4*)a2 = w2[f4];
            #pragma unroll
            for (int j = 0; j < 4; ++j) {
                int f = f4 * 4 + j;
                float f0 = form_s[f * 33 + r];
                float fm = __shfl_up(f0, 1, 32);   if (r == 0)  fm = 0.f;
                float fp = __shfl_down(f0, 1, 32); if (r == 31) fp = 0.f;
                s0 += a0[j] * fm; s1 += a1[j] * f0; s2 += a2[j] * fp;
            }
        }
        S.match_s[p * 32 + r] = __expf(lsg(s0) + lsg(s1) + lsg(s2));
    }
    __syncthreads();

    // ---- coef + rlI precompute + register caching (before U overlay) ----
    if (t < 96) {
        int sub = t >> 5, r = t & 31;
        const float* w = (sub == 0) ? S.wep0_s : (sub == 1) ? S.wdl_s : S.wep2_s;
        float s = 0.f;
        for (int p = 0; p < 16; ++p) s += S.match_s[p * 32 + r] * w[p];
        float cf;
        if (sub == 1) cf = 1.f - sigm(s - S.sc_s[0]);   // 1 - p_deln
        else          cf = sigm(s - S.sc_s[1]);         // p_epen
        S.coef_s[sub * 32 + r] = cf;
    }
    for (int i = t; i < 512; i += 256) {
        int p = i >> 5, r = i & 31;
        float m = S.match_s[p * 32 + r];
        rlI[2 * i]     = fmaxf(m * S.wep0_s[p], 0.f);
        rlI[2 * i + 1] = fmaxf(m * S.wep2_s[p], 0.f);
    }
    float wchf[16], vchf[16];
    #pragma unroll
    for (int p = 0; p < 16; ++p) {
        wchf[p] = wch_s[p * 64 + f_own];
        vchf[p] = vch_s[p * 64 + f_own];
    }
    const float wncf = S.wnc_s[f_own];
    float si_r[8];                                 // form dies at U overlay
    #pragma unroll
    for (int j = 0; j < 8; ++j) si_r[j] = form_s[f_own * 33 + fq * 8 + j];
    __syncthreads();

    // ---- xtab: per-thread fixed f, 8 rs values (overlays U) ----
    #pragma unroll 1
    for (int j = 0; j < 8; ++j) {
        int rs = fq * 8 + j;                       // wave-uniform
        v2f v02; v02.x = 0.f; v02.y = 0.f;
        float sum = 0.f, vs1 = 0.f;
        const v2f* rlp = (const v2f*)(rlI + 2 * rs);
        #pragma unroll
        for (int p = 0; p < 16; ++p) {
            v2f rl = rlp[p * 32];                  // broadcast b64
            v02 += rl * vepf[p];
            float m = S.match_s[p * 32 + rs];      // broadcast b32
            float wc = m * wchf[p];
            sum += wc;
            vs1 += fmaxf(wc, 0.f) * vchf[p];
        }
        float pch = sigm(sum - wncf);
        float si  = si_r[j];
        xtab[0 * 2048 + rs * 64 + f_own] = v02.x;
        xtab[1 * 2048 + rs * 64 + f_own] = si + pch * (vs1 - si);
        xtab[2 * 2048 + rs * 64 + f_own] = v02.y;
    }
    __syncthreads();

    // ---- k-ordered coefs (k = rs*3+sub) + exclusive prefix (posn) ----
    float* ck_s  = S.match_s;        // match dead after xtab
    float* pos_s = S.match_s + 128;
    if (t < 96) ck_s[t] = S.coef_s[(t % 3) * 32 + (t / 3)];
    __syncthreads();
    if (t < 64) {
        float a = ck_s[t];
        float a0 = a;
        #pragma unroll
        for (int d = 1; d < 64; d <<= 1) { float v = __shfl_up(a, d, 64); if (t >= d) a += v; }
        pos_s[t] = a - a0;                          // exclusive prefix
        float carry = __shfl(a, 63, 64);            // inclusive sum of first 64
        float b2 = (t < 32) ? ck_s[64 + t] : 0.f;
        float c2 = b2;
        #pragma unroll
        for (int d = 1; d < 32; d <<= 1) { float v = __shfl_up(c2, d, 32); if ((t & 31) >= d) c2 += v; }
        if (t < 32) pos_s[64 + t] = carry + c2 - b2;
    }
    __syncthreads();

    // ---- gtab[k][r]: all 96 softmax-gates in parallel (overlays V) ----
    #pragma unroll 1
    for (int i = 0; i < 12; ++i) {
        int idx = t + 256 * i;                      // k = idx>>5, r = idx&31
        int k = idx >> 5, r = idx & 31;
        float posn = pos_s[k];
        float pc = fminf(posn, 31.f);
        float ci = floorf(pc + 0.5f);
        float dmin = posn - ci;
        float dd = posn - (float)r;
        float eo = __expf(-2.f * (dd * dd - dmin * dmin));   // exact, max-subtracted
        float Z = eo;
        Z += __shfl_xor(Z, 1, 32);
        Z += __shfl_xor(Z, 2, 32);
        Z += __shfl_xor(Z, 4, 32);
        Z += __shfl_xor(Z, 8, 32);
        Z += __shfl_xor(Z, 16, 32);
        gtab[idx] = ck_s[k] * eo / Z;
    }
    __syncthreads();

    // ---- phase D: pure-throughput blend ----
    const int fgrp = t >> 5;
    v2f o01, o23, o45, o67;
    o01 = 0.f; o23 = 0.f; o45 = 0.f; o67 = 0.f;
    #pragma unroll 1
    for (int rs = 0; rs < 32; ++rs) {
        #pragma unroll
        for (int sub = 0; sub < 3; ++sub) {
            float g = gtab[(rs * 3 + sub) * 32 + my_r];
            v2f gv; gv.x = g; gv.y = g;
            const float4* xb = (const float4*)(xtab + sub * 2048 + rs * 64 + fgrp * 8);
            float4 xa = xb[0], xc = xb[1];
            v2f x01, x23, x45, x67;
            x01.x = xa.x; x01.y = xa.y; x23.x = xa.z; x23.y = xa.w;
            x45.x = xc.x; x45.y = xc.y; x67.x = xc.z; x67.y = xc.w;
            o01 += gv * (x01 - o01);
            o23 += gv * (x23 - o23);
            o45 += gv * (x45 - o45);
            o67 += gv * (x67 - o67);
        }
    }

    float oreg[8] = {o01.x, o01.y, o23.x, o23.y, o45.x, o45.y, o67.x, o67.y};
    #pragma unroll
    for (int i = 0; i < 8; ++i) {
        ST<F32>(A.outp, b * 2048 + (fgrp * 8 + i) * 32 + my_r, oreg[i]);
    }
}

__global__ __launch_bounds__(256) void scan_kernel(Args A, const float* Y) {
    __shared__ ScanSmem S;
    __shared__ int dt_s;
    const int t = threadIdx.x, b = blockIdx.x;
    int isf32 = probe_is_f32(A.ctx, t, &dt_s);
    if (isf32) scan_body<true>(S, t, b, A, Y);
    else       scan_body<false>(S, t, b, A, Y);
}

// ---------------- Last-resort monolithic fallback (round-2, proven) ---------
struct Smem {
    float U[6144];
    float form_s[64 * 33];
    float match_s[512];
    float wch_s[1024];
    float vch_s[1024];
    float vep0_s[1024];
    float vep2_s[1024];
    float wep0_s[16], wep2_s[16], wdl_s[16];
    float wnc_s[64];
    float sc_s[2];
    float ssum_s[96];
};

template<bool F32>
__device__ void mono_body(Smem& S, int t, int b, const Args& A) {
    float* c_s  = S.U;
    float* modl = S.U + 128;
    float* Wk_s = S.U + 224;
    float* bk_s = S.U + 3344;
    float* xtab = S.U;

    if (t < 128) c_s[t] = LD<F32>(A.ctx, b * 128 + t);
    {
        int e0 = b * 2048 + t * 8;
        float4 x = LD4<F32>(A.form, e0);
        float4 y = LD4<F32>(A.form, e0 + 4);
        int f = t >> 2, r0 = (t & 3) * 8;
        float* dst = S.form_s + f * 33 + r0;
        dst[0] = x.x; dst[1] = x.y; dst[2] = x.z; dst[3] = x.w;
        dst[4] = y.x; dst[5] = y.y; dst[6] = y.z; dst[7] = y.w;
    }
    __syncthreads();
    if (t < 96) {
        float a = LD<F32>(A.mod_b, t);
        for (int cc = 0; cc < 128; ++cc) a += c_s[cc] * LD<F32>(A.mod_W, cc * 96 + t);
        modl[t] = a;
    }
    __syncthreads();
    if (t < 16) {
        float v[6]; float mx = -1e30f;
        #pragma unroll
        for (int j = 0; j < 6; ++j) { v[j] = modl[t * 6 + j]; mx = fmaxf(mx, v[j]); }
        float s = 0.f;
        #pragma unroll
        for (int j = 0; j < 6; ++j) { v[j] = __expf(v[j] - mx); s += v[j]; }
        float inv = 1.f / s;
        #pragma unroll
        for (int j = 0; j < 6; ++j) modl[t * 6 + j] = v[j] * inv;
    }
    __syncthreads();
    for (int j = t; j < 512; j += 256) {
        int n0 = j * 2;
        float2 bb = LD2<F32>(A.wch_b, n0);
        float a0 = bb.x, a1 = bb.y;
        for (int cc = 0; cc < 128; ++cc) {
            float2 w = LD2<F32>(A.wch_W, cc * 1024 + n0); float cv = c_s[cc];
            a0 += cv * w.x; a1 += cv * w.y;
        }
        int p = n0 >> 6; float sc = modl[p * 6 + 0];
        S.wch_s[n0] = sc * a0; S.wch_s[n0 + 1] = sc * a1;
    }
    for (int j = t; j < 512; j += 256) {
        int n0 = j * 2;
        float2 bb = LD2<F32>(A.vch_b, n0);
        float a0 = bb.x, a1 = bb.y;
        for (int cc = 0; cc < 128; ++cc) {
            float2 w = LD2<F32>(A.vch_W, cc * 1024 + n0); float cv = c_s[cc];
            a0 += cv * w.x; a1 += cv * w.y;
        }
        S.vch_s[n0] = a0; S.vch_s[n0 + 1] = a1;
    }
    for (int u = t; u < 1024; u += 256) {
        int n0 = u * 4;
        float4 bb = LD4<F32>(A.vep_b, n0);
        float a0 = bb.x, a2 = bb.z;
        for (int cc = 0; cc < 128; ++cc) {
            float4 w = LD4<F32>(A.vep_W, cc * 4096 + n0); float cv = c_s[cc];
            a0 += cv * w.x; a2 += cv * w.z;
        }
        S.vep0_s[u] = a0; S.vep2_s[u] = a2;
    }
    for (int j = t; j < 1536; j += 256) {
        int k  = j >> 9;
        int jj = j & 511;
        int n0 = jj * 2;
        float2 bb = LD2<F32>(A.m_Wb, k * 1024 + n0);
        float a0 = bb.x, a1 = bb.y;
        for (int cc = 0; cc < 128; ++cc) {
            float2 w = LD2<F32>(A.m_W, (k * 128 + cc) * 1024 + n0); float cv = c_s[cc];
            a0 += cv * w.x; a1 += cv * w.y;
        }
        int p = n0 >> 6, f = n0 & 63;
        Wk_s[(k * 16 + p) * 65 + f]     = a0;
        Wk_s[(k * 16 + p) * 65 + f + 1] = a1;
    }
    if (t < 16) {
        int n0 = t * 4;
        float4 bb = LD4<F32>(A.wep_b, n0);
        float a0 = bb.x, a2 = bb.z;
        for (int cc = 0; cc < 128; ++cc) {
            float4 w = LD4<F32>(A.wep_W, cc * 64 + n0); float cv = c_s[cc];
            a0 += cv * w.x; a2 += cv * w.z;
        }
        S.wep0_s[t] = modl[t * 6 + 2] * a0;
        S.wep2_s[t] = modl[t * 6 + 4] * a2;
    } else if (t < 32) {
        int p = t - 16;
        float a = LD<F32>(A.wdl_b, p);
        for (int cc = 0; cc < 128; ++cc) a += c_s[cc] * LD<F32>(A.wdl_W, cc * 16 + p);
        S.wdl_s[p] = modl[p * 6 + 1] * a;
    } else if (t < 96) {
        int f = t - 32;
        float a = LD<F32>(A.wnc_b, f);
        for (int cc = 0; cc < 128; ++cc) a += c_s[cc] * LD<F32>(A.wnc_W, cc * 64 + f);
        S.wnc_s[f] = __expf(a);
    } else if (t < 98) {
        const void* W  = (t == 96) ? A.wnd_W : A.wne_W;
        const void* bb = (t == 96) ? A.wnd_b : A.wne_b;
        float a = LD<F32>(bb, 0);
        for (int cc = 0; cc < 128; ++cc) a += c_s[cc] * LD<F32>(W, cc);
        S.sc_s[t - 96] = __expf(a);
    } else if (t < 146) {
        int i = t - 98;
        int k = i >> 4, p = i & 15;
        float a = LD<F32>(A.mb_b, k * 16 + p);
        for (int cc = 0; cc < 128; ++cc) a += c_s[cc] * LD<F32>(A.mb_W, (k * 128 + cc) * 16 + p);
        bk_s[i] = a;
    }
    __syncthreads();
    for (int idx = t; idx < 512; idx += 256) {
        int p = idx >> 5, r = idx & 31;
        float s0 = bk_s[p], s1 = bk_s[16 + p], s2 = bk_s[32 + p];
        const float* w0 = Wk_s + p * 65;
        const float* w1 = Wk_s + (16 + p) * 65;
        const float* w2 = Wk_s + (32 + p) * 65;
        for (int f = 0; f < 64; ++f) {
            const float* fr = S.form_s + f * 33 + r;
            float fm1 = (r > 0)  ? fr[-1] : 0.f;
            float f0  = fr[0];
            float fp1 = (r < 31) ? fr[1]  : 0.f;
            s0 += w0[f] * fm1; s1 += w1[f] * f0; s2 += w2[f] * fp1;
        }
        S.match_s[p * 32 + r] = __expf(lsg(s0) + lsg(s1) + lsg(s2));
    }
    __syncthreads();
    if (t < 96) {
        int which = t >> 5, r = t & 31;
        const float* w = (which == 0) ? S.wep0_s : (which == 1) ? S.wep2_s : S.wdl_s;
        float s = 0.f;
        for (int p = 0; p < 16; ++p) s += S.match_s[p * 32 + r] * w[p];
        S.ssum_s[which * 32 + r] = s;
    }
    #pragma unroll 1
    for (int q = 0; q < 24; ++q) {
        int idx = t + 256 * q;
        int sub = idx >> 11;
        int rs  = (idx >> 6) & 31;
        int f   = idx & 63;
        float x;
        if (sub == 1) {
            float sum = 0.f, vs = 0.f;
            for (int p = 0; p < 16; ++p) {
                float wc = S.match_s[p * 32 + rs] * S.wch_s[p * 64 + f];
                sum += wc;
                vs  += fmaxf(wc, 0.f) * S.vch_s[p * 64 + f];
            }
            float pch = sigm(sum - S.wnc_s[f]);
            float si  = S.form_s[f * 33 + rs];
            x = si + pch * (vs - si);
        } else {
            const float* wep = (sub == 0) ? S.wep0_s : S.wep2_s;
            const float* vep = (sub == 0) ? S.vep0_s : S.vep2_s;
            float vs = 0.f;
            for (int p = 0; p < 16; ++p) {
                float w = S.match_s[p * 32 + rs] * wep[p];
                vs += fmaxf(w, 0.f) * vep[p * 64 + f];
            }
            x = vs;
        }
        xtab[idx] = x;
    }
    __syncthreads();
    const int my_r = t & 31;
    const int fgrp = t >> 5;
    float oreg[8];
    #pragma unroll
    for (int i = 0; i < 8; ++i) oreg[i] = 0.f;
    float posn = 0.f;
    const float wnd1v = S.sc_s[0];
    const float wne1v = S.sc_s[1];
    for (int rs = 0; rs < 32; ++rs) {
        #pragma unroll
        for (int sub = 0; sub < 3; ++sub) {
            float coef;
            if (sub == 1) coef = 1.f - sigm(S.ssum_s[64 + rs] - wnd1v);
            else          coef = sigm(S.ssum_s[(sub & 2) * 16 + rs] - wne1v);
            float pc = fminf(posn, 31.f);
            int ci = (int)(pc + 0.5f);
            int lo = ci - 4; if (lo < 0)  lo = 0;
            int hi = ci + 4; if (hi > 31) hi = 31;
            float dmin = posn - (float)ci;
            float mx = -2.f * dmin * dmin;
            float Z = 0.f, eo = 0.f;
            for (int r = lo; r <= hi; ++r) {
                float d = posn - (float)r;
                float e = __expf(-2.f * d * d - mx);
                Z += e;
                if (r == my_r) eo = e;
            }
            float g = coef * eo / Z;
            const float* xb = xtab + (sub * 2048 + rs * 64 + fgrp * 8);
            #pragma unroll
            for (int i = 0; i < 8; ++i) oreg[i] += g * (xb[i] - oreg[i]);
            posn += coef;
        }
    }
    #pragma unroll
    for (int i = 0; i < 8; ++i) {
        ST<F32>(A.outp, b * 2048 + (fgrp * 8 + i) * 32 + my_r, oreg[i]);
    }
}

__global__ __launch_bounds__(256) void phon_mono(Args A) {
    __shared__ Smem S;
    __shared__ int dt_s;
    const int t = threadIdx.x, b = blockIdx.x;
    int isf32 = probe_is_f32(A.ctx, t, &dt_s);
    if (isf32) mono_body<true>(S, t, b, A);
    else       mono_body<false>(S, t, b, A);
}

extern "C" void kernel_launch(void* const* d_in, const int* in_sizes, int n_in,
                              void* d_out, int out_size, void* d_ws, size_t ws_size,
                              hipStream_t stream) {
    Args A;
    A.form  = d_in[0];  A.ctx   = d_in[1];
    A.mod_W = d_in[2];  A.mod_b = d_in[3];
    A.wch_W = d_in[4];  A.wch_b = d_in[5];
    A.wdl_W = d_in[6];  A.wdl_b = d_in[7];
    A.wep_W = d_in[8];  A.wep_b = d_in[9];
    A.vch_W = d_in[10]; A.vch_b = d_in[11];
    A.vep_W = d_in[12]; A.vep_b = d_in[13];
    A.wnc_W = d_in[14]; A.wnc_b = d_in[15];
    A.wnd_W = d_in[16]; A.wnd_b = d_in[17];
    A.wne_W = d_in[18]; A.wne_b = d_in[19];
    A.m_W   = d_in[20]; A.m_Wb  = d_in[21];
    A.mb_W  = d_in[22]; A.mb_b  = d_in[23];
    A.outp  = d_out;

    const size_t yElems  = (size_t)B_ * YS3;        // floats
    const size_t bpElems = (size_t)NT * 4096;       // u16
    const size_t need = yElems * 4 + bpElems * 2 + (size_t)YS3 * 4;
    if (ws_size >= need) {
        float* Y     = (float*)d_ws;
        u16*   Bpack = (u16*)(Y + yElems);
        float* bcat  = (float*)(Bpack + bpElems);
        packw_kernel<<<NT, 256, 0, stream>>>(A, Bpack, bcat);
        gemm_mfma_kernel<<<30 * 128, 256, 0, stream>>>(A, Bpack, bcat, Y);
        scan_kernel<<<B_, 256, 0, stream>>>(A, Y);
    } else {
        phon_mono<<<B_, 256, 0, stream>>>(A);
    }
}

// Round 10
// 235.985 us; speedup vs baseline: 1.9973x; 1.0331x over previous
//
#include <hip/hip_runtime.h>

// Problem constants: B=2048, F=64, R=32, P=16, C=128, TAU=2.0
#define B_ 2048
#define YS3 7440   // Y stride = 465 tiles x 16
#define NT  465

typedef unsigned short u16;
typedef unsigned int   u32;
typedef __attribute__((ext_vector_type(2))) float v2f;
typedef __attribute__((ext_vector_type(8))) short bf16x8;  // 8 bf16 = 4 VGPR
typedef __attribute__((ext_vector_type(4))) float f32x4;

__device__ __forceinline__ float bfu(u16 u) {
    u32 i = ((u32)u) << 16; float f; __builtin_memcpy(&f, &i, 4); return f;
}
__device__ __forceinline__ u16 f2bf(float v) {
    u32 iv; __builtin_memcpy(&iv, &v, 4);
    u32 r = (iv + 0x7fffu + ((iv >> 16) & 1u)) >> 16;
    return (u16)r;
}
__device__ __forceinline__ float sigm(float x) { return 1.f / (1.f + __expf(-x)); }
__device__ __forceinline__ float lsg(float x) {
    return fminf(x, 0.f) - log1pf(__expf(-fabsf(x)));
}

template<bool F32> __device__ __forceinline__ float LD(const void* p, int e) {
    if (F32) return ((const float*)p)[e];
    return bfu(((const u16*)p)[e]);
}
template<bool F32> __device__ __forceinline__ float2 LD2(const void* p, int e) { // e even
    if (F32) { const float* q = (const float*)p; return make_float2(q[e], q[e + 1]); }
    u32 w = ((const u32*)p)[e >> 1];
    u32 lo = w << 16, hi = w & 0xffff0000u; float a, b;
    __builtin_memcpy(&a, &lo, 4); __builtin_memcpy(&b, &hi, 4);
    return make_float2(a, b);
}
template<bool F32> __device__ __forceinline__ float4 LD4(const void* p, int e) { // e%4==0
    if (F32) return ((const float4*)p)[e >> 2];
    uint2 w = ((const uint2*)p)[e >> 2];
    u32 a0 = w.x << 16, a1 = w.x & 0xffff0000u, a2 = w.y << 16, a3 = w.y & 0xffff0000u;
    float f0, f1, f2, f3;
    __builtin_memcpy(&f0, &a0, 4); __builtin_memcpy(&f1, &a1, 4);
    __builtin_memcpy(&f2, &a2, 4); __builtin_memcpy(&f3, &a3, 4);
    return make_float4(f0, f1, f2, f3);
}
template<bool F32> __device__ __forceinline__ void ST(void* p, int e, float v) {
    if (F32) ((float*)p)[e] = v; else ((u16*)p)[e] = f2bf(v);
}

struct Args {
    const void *form, *ctx;
    const void *mod_W, *mod_b, *wch_W, *wch_b, *wdl_W, *wdl_b, *wep_W, *wep_b;
    const void *vch_W, *vch_b, *vep_W, *vep_b;
    const void *wnc_W, *wnc_b, *wnd_W, *wnd_b, *wne_W, *wne_b;
    const void *m_W, *m_Wb, *mb_W, *mb_b;
    void* outp;
};

// dtype probe: block-uniform, deterministic. Returns 1 if inputs are fp32.
__device__ __forceinline__ int probe_is_f32(const void* ctx, int t, int* flag_s) {
    if (t == 0) {
        int sane = 0;
        const u16* q = (const u16*)ctx;
        for (int i = 0; i < 64; ++i) {
            u16 u = q[2 * i];
            int ex = (u >> 7) & 0xFF;
            sane += (u == 0 || (ex >= 112 && ex <= 143)) ? 1 : 0;
        }
        *flag_s = (sane < 32) ? 1 : 0;
    }
    __syncthreads();
    return *flag_s;
}

// hi/lo bf16 split (Markidis): x ~= hi + lo, |err| ~ 2^-18 |x|
__device__ __forceinline__ void split_bf16(float x, u16& hi, u16& lo) {
    hi = f2bf(x);
    lo = f2bf(x - bfu(hi));
}

// ============================================================================
// Y column map, n in [0,7440):
//  [0,1024) wch | [1024,2048) vch | [2048,4096) vepI (2048+2u+s <- vep 4u+2s)
//  [4096,7168) Wk (4096+k*1024+j <- m_W[k][.][j]) | [7168,7264) mod
//  [7264,7312) bk (k*16+p <- mb_W) | [7312,7344) wepI (7312+2u+s <- wep 4u+2s)
//  [7344,7360) wdl | [7360,7424) wnc | [7424] wnd | [7425] wne | [7426,7440) 0
// ============================================================================

// ---------------- Kernel R1: pack W -> Bpack[T][h][kb][l][8] bf16 -----------
template<bool F32>
__device__ void packw_body(int g, const Args& A, u16* Bpack, float* bcat) {
    int l  = g & 63;
    int kb = (g >> 6) & 3;
    int T  = g >> 8;                      // 0..464
    int n  = T * 16 + (l & 15);
    int k0 = kb * 32 + (l >> 4) * 8;

    const void* p = A.wch_W; int off = 0, st = 0, zero = 0; float bb = 0.f;
    if (n < 1024)      { off = n; st = 1024; bb = LD<F32>(A.wch_b, n); }
    else if (n < 2048) { int j = n - 1024; p = A.vch_W; off = j; st = 1024; bb = LD<F32>(A.vch_b, j); }
    else if (n < 4096) { int i = n - 2048; int col = 4 * (i >> 1) + 2 * (i & 1);
                         p = A.vep_W; off = col; st = 4096; bb = LD<F32>(A.vep_b, col); }
    else if (n < 7168) { int i = n - 4096; int kk = i >> 10, j = i & 1023;
                         p = A.m_W; off = kk * 131072 + j; st = 1024; bb = LD<F32>(A.m_Wb, kk * 1024 + j); }
    else if (n < 7264) { int m = n - 7168; p = A.mod_W; off = m; st = 96; bb = LD<F32>(A.mod_b, m); }
    else if (n < 7312) { int i = n - 7264; int k = i >> 4, pp = i & 15;
                         p = A.mb_W; off = k * 2048 + pp; st = 16; bb = LD<F32>(A.mb_b, k * 16 + pp); }
    else if (n < 7344) { int i = n - 7312; int col = 4 * (i >> 1) + 2 * (i & 1);
                         p = A.wep_W; off = col; st = 64; bb = LD<F32>(A.wep_b, col); }
    else if (n < 7360) { int j = n - 7344; p = A.wdl_W; off = j; st = 16; bb = LD<F32>(A.wdl_b, j); }
    else if (n < 7424) { int j = n - 7360; p = A.wnc_W; off = j; st = 64; bb = LD<F32>(A.wnc_b, j); }
    else if (n == 7424){ p = A.wnd_W; off = 0; st = 1; bb = LD<F32>(A.wnd_b, 0); }
    else if (n == 7425){ p = A.wne_W; off = 0; st = 1; bb = LD<F32>(A.wne_b, 0); }
    else zero = 1;

    u16 hi[8], lo[8];
    #pragma unroll
    for (int j = 0; j < 8; ++j) {
        float w = LD<F32>(p, off + (k0 + j) * st);
        if (zero) w = 0.f;
        split_bf16(w, hi[j], lo[j]);
    }
    *(uint4*)(Bpack + ((size_t)T * 512 + kb * 64 + l) * 8)       = *(const uint4*)hi;
    *(uint4*)(Bpack + ((size_t)T * 512 + 256 + kb * 64 + l) * 8) = *(const uint4*)lo;
    if (kb == 0 && l < 16) bcat[n] = zero ? 0.f : bb;
}

__global__ __launch_bounds__(256) void packw_kernel(Args A, u16* Bpack, float* bcat) {
    __shared__ int dt_s;
    const int t = threadIdx.x;
    int isf32 = probe_is_f32(A.ctx, t, &dt_s);
    int g = blockIdx.x * 256 + t;
    if (isf32) packw_body<true>(g, A, Bpack, bcat);
    else       packw_body<false>(g, A, Bpack, bcat);
}

// ---------------- Kernel G: MFMA GEMM  Y = ctx @ W + b (split-bf16 3-pass) --
template<bool F32>
__device__ void gemm_mfma_body(float* As, int t, int blk, const void* __restrict__ ctx,
                               const u16* __restrict__ Bpack,
                               const float* __restrict__ bcat, float* __restrict__ Y) {
    const int l  = t & 63;
    const int w  = t >> 6;
    const int Mt = blk & 127;
    const int nb = blk >> 7;

    {
        int row = t >> 4, c0 = (t & 15) * 8;
        float4 x = LD4<F32>(ctx, (Mt * 16 + row) * 128 + c0);
        float4 y = LD4<F32>(ctx, (Mt * 16 + row) * 128 + c0 + 4);
        *(float4*)&As[row * 132 + c0]     = x;
        *(float4*)&As[row * 132 + c0 + 4] = y;
    }
    __syncthreads();

    bf16x8 ahi[4], alo[4];
    const int m = l & 15;
    #pragma unroll
    for (int kb = 0; kb < 4; ++kb) {
        int k0 = kb * 32 + (l >> 4) * 8;
        const float* ap = &As[m * 132 + k0];
        #pragma unroll
        for (int j = 0; j < 8; ++j) {
            u16 hi, lo; split_bf16(ap[j], hi, lo);
            ahi[kb][j] = (short)hi;
            alo[kb][j] = (short)lo;
        }
    }

    const int Tbase = nb * 16 + w * 4;
    const int row0  = Mt * 16 + (l >> 4) * 4;
    const int ncol  = l & 15;

    #pragma unroll
    for (int T = 0; T < 4; ++T) {
        int Tt = Tbase + T;
        if (Tt >= NT) break;
        const u16* Bb = Bpack + (size_t)Tt * 4096;
        bf16x8 bhi[4], blo[4];
        #pragma unroll
        for (int kb = 0; kb < 4; ++kb) {
            bhi[kb] = *(const bf16x8*)(Bb + ((kb) * 64 + l) * 8);
            blo[kb] = *(const bf16x8*)(Bb + ((4 + kb) * 64 + l) * 8);
        }
        f32x4 d = {0.f, 0.f, 0.f, 0.f};
        #pragma unroll
        for (int kb = 0; kb < 4; ++kb) {
            d = __builtin_amdgcn_mfma_f32_16x16x32_bf16(ahi[kb], bhi[kb], d, 0, 0, 0);
            d = __builtin_amdgcn_mfma_f32_16x16x32_bf16(ahi[kb], blo[kb], d, 0, 0, 0);
            d = __builtin_amdgcn_mfma_f32_16x16x32_bf16(alo[kb], bhi[kb], d, 0, 0, 0);
        }
        int n = Tt * 16 + ncol;
        float bv = bcat[n];
        #pragma unroll
        for (int i = 0; i < 4; ++i) {
            Y[(size_t)(row0 + i) * YS3 + n] = d[i] + bv;
        }
    }
}

__global__ __launch_bounds__(256) void gemm_mfma_kernel(Args A, const u16* Bpack,
                                                        const float* bcat, float* Y) {
    __shared__ float As[16 * 132];
    __shared__ int dt_s;
    const int t = threadIdx.x, blk = blockIdx.x;
    int isf32 = probe_is_f32(A.ctx, t, &dt_s);
    if (isf32) gemm_mfma_body<true>(As, t, blk, A.ctx, Bpack, bcat, Y);
    else       gemm_mfma_body<false>(As, t, blk, A.ctx, Bpack, bcat, Y);
}

// ============================================================================
// Kernel 2: MFMA-match + xtab(p-outer) + parallel-gated scan
// LDS (~39.8 KB -> 4 blocks/CU):
//   U[6144]: bk@0(48) modl@48(96) form@144(64x34, zero guard cols 0 & 33)
//            -> after match phase, U overlaid by xtab[6144]
//   V[3072]: wch@0(1024) vch@1024(1024) rlI@2048(1024) -> gtab[3072] in D
// ============================================================================
struct __align__(16) ScanSmem {
    float U[6144];
    float V[3072];
    float match_s[512];     // [p][r]; later ck@0(96) pos@128(96)
    float wnc_s[64];
    float wep0_s[16], wep2_s[16], wdl_s[16];
    float coef_s[96];       // [sub][rs] (sub 0:ep0, 1:deln, 2:ep2)
    float sc_s[2];          // {w_nodeln, w_noepen}
};

template<bool F32>
__device__ void scan_body(ScanSmem& S, int t, int b, const Args& A, const float* __restrict__ Y) {
    float* bk_s   = S.U;           // 48
    float* modl   = S.U + 48;      // 96
    float* form_s = S.U + 144;     // 64 x 34, col 0 and 33 zero guards
    float* xtab   = S.U;           // overlay after match phase
    float* wch_s  = S.V;
    float* vch_s  = S.V + 1024;
    float* rlI    = S.V + 2048;    // relu(match*wep) interleaved pairs
    float* gtab   = S.V;           // overlay in phase D

    const float* Yr = Y + (size_t)b * YS3;
    const float4* Y4 = (const float4*)Yr;

    const int f_own = t & 63;
    const int fq    = t >> 6;
    const int l     = t & 63;
    const int wv    = t >> 6;
    const int my_r  = t & 31;

    // ---- stage form (pitch 34 + guards) + Y segments into LDS ----
    if (t < 64) { form_s[t * 34] = 0.f; form_s[t * 34 + 33] = 0.f; }
    {
        int e0 = b * 2048 + t * 8;
        float4 x = LD4<F32>(A.form, e0);
        float4 y = LD4<F32>(A.form, e0 + 4);
        int f = t >> 2, r0 = (t & 3) * 8;
        float* dst = form_s + f * 34 + 1 + r0;
        dst[0] = x.x; dst[1] = x.y; dst[2] = x.z; dst[3] = x.w;
        dst[4] = y.x; dst[5] = y.y; dst[6] = y.z; dst[7] = y.w;
    }
    if (t < 12) ((float4*)bk_s)[t] = Y4[1816 + t];                           // bk @7264
    else if (t >= 32 && t < 56) ((float4*)modl)[t - 32] = Y4[1792 + (t - 32)]; // mod @7168
    ((float4*)wch_s)[t] = Y4[t];                                             // wch @0
    ((float4*)vch_s)[t] = Y4[256 + t];                                       // vch @1024
    if (t >= 64 && t < 80) {
        int p = t - 64;
        S.wep0_s[p] = Yr[7312 + 2 * p];
        S.wep2_s[p] = Yr[7312 + 2 * p + 1];
        S.wdl_s[p]  = Yr[7344 + p];
    } else if (t >= 96 && t < 160) {
        S.wnc_s[t - 96] = __expf(Yr[7360 + (t - 96)]);
    } else if (t >= 160 && t < 162) {
        S.sc_s[t - 160] = __expf(Yr[7424 + (t - 160)]);
    }
    __syncthreads();

    // ---- softmax(6) on mod ----
    if (t < 16) {
        float v[6]; float mx = -1e30f;
        #pragma unroll
        for (int j = 0; j < 6; ++j) { v[j] = modl[t * 6 + j]; mx = fmaxf(mx, v[j]); }
        float s = 0.f;
        #pragma unroll
        for (int j = 0; j < 6; ++j) { v[j] = __expf(v[j] - mx); s += v[j]; }
        float inv = 1.f / s;
        #pragma unroll
        for (int j = 0; j < 6; ++j) modl[t * 6 + j] = v[j] * inv;
    }
    __syncthreads();

    // ---- mod scaling + MFMA match (waves 0,1) ----
    if (t < 16) {
        S.wep0_s[t] *= modl[t * 6 + 2];
        S.wep2_s[t] *= modl[t * 6 + 4];
        S.wdl_s[t]  *= modl[t * 6 + 1];
    }
    for (int i = t; i < 1024; i += 256) wch_s[i] *= modl[(i >> 6) * 6];

    if (wv < 2) {
        // score[k][p][r] = bk[k][p] + sum_f Wk[k][p][f] * form3[k][f][r]
        // A = Wk (m=p, frag: lane l&15 = p, k = quad*8+j) from global Y
        // B = form3 (n=r, frag: lane l&15 = col, k = quad*8+j) from LDS form
        // D: row = quad*4+i = p, col = l&15 -> r = wv*16 + (l&15)
        const int q  = l >> 4;
        const int rb = wv * 16 + (l & 15);
        f32x4 msum = {0.f, 0.f, 0.f, 0.f};
        #pragma unroll
        for (int kmat = 0; kmat < 3; ++kmat) {
            f32x4 d = {0.f, 0.f, 0.f, 0.f};
            #pragma unroll
            for (int kb = 0; kb < 2; ++kb) {
                const float* ap = Yr + 4096 + kmat * 1024 + (l & 15) * 64 + kb * 32 + q * 8;
                float4 a0 = *(const float4*)ap;
                float4 a1 = *(const float4*)(ap + 4);
                float av[8] = {a0.x, a0.y, a0.z, a0.w, a1.x, a1.y, a1.z, a1.w};
                bf16x8 Ahi, Alo, Bhi, Blo;
                #pragma unroll
                for (int j = 0; j < 8; ++j) {
                    u16 hi, lo; split_bf16(av[j], hi, lo);
                    Ahi[j] = (short)hi; Alo[j] = (short)lo;
                }
                int coladdr = rb + kmat;       // form[f][rb + (kmat-1)], +1 guard base
                #pragma unroll
                for (int j = 0; j < 8; ++j) {
                    int f = kb * 32 + q * 8 + j;
                    float v = form_s[f * 34 + coladdr];
                    u16 hi, lo; split_bf16(v, hi, lo);
                    Bhi[j] = (short)hi; Blo[j] = (short)lo;
                }
                d = __builtin_amdgcn_mfma_f32_16x16x32_bf16(Ahi, Bhi, d, 0, 0, 0);
                d = __builtin_amdgcn_mfma_f32_16x16x32_bf16(Ahi, Blo, d, 0, 0, 0);
                d = __builtin_amdgcn_mfma_f32_16x16x32_bf16(Alo, Bhi, d, 0, 0, 0);
            }
            #pragma unroll
            for (int i = 0; i < 4; ++i) {
                msum[i] += lsg(d[i] + bk_s[kmat * 16 + q * 4 + i]);
            }
        }
        #pragma unroll
        for (int i = 0; i < 4; ++i) {
            S.match_s[(q * 4 + i) * 32 + rb] = __expf(msum[i]);
        }
    }
    __syncthreads();

    // ---- coef + rlI precompute + register caching (before U overlay) ----
    if (t < 96) {
        int sub = t >> 5, r = t & 31;
        const float* w = (sub == 0) ? S.wep0_s : (sub == 1) ? S.wdl_s : S.wep2_s;
        float s = 0.f;
        for (int p = 0; p < 16; ++p) s += S.match_s[p * 32 + r] * w[p];
        float cf;
        if (sub == 1) cf = 1.f - sigm(s - S.sc_s[0]);   // 1 - p_deln
        else          cf = sigm(s - S.sc_s[1]);         // p_epen
        S.coef_s[sub * 32 + r] = cf;
    }
    for (int i = t; i < 512; i += 256) {
        int p = i >> 5, r = i & 31;
        float m = S.match_s[p * 32 + r];
        rlI[2 * i]     = fmaxf(m * S.wep0_s[p], 0.f);
        rlI[2 * i + 1] = fmaxf(m * S.wep2_s[p], 0.f);
    }
    // vep pairs straight from global Y (coalesced b64)
    const float2* vep2p = (const float2*)(Yr + 2048);
    v2f vepf[16];
    #pragma unroll
    for (int p = 0; p < 16; ++p) {
        float2 v = vep2p[p * 64 + f_own];
        vepf[p].x = v.x; vepf[p].y = v.y;
    }
    float wchf[16], vchf[16];
    #pragma unroll
    for (int p = 0; p < 16; ++p) {
        wchf[p] = wch_s[p * 64 + f_own];
        vchf[p] = vch_s[p * 64 + f_own];
    }
    const float wncf = S.wnc_s[f_own];
    float si_r[8];                                 // form dies at U overlay
    #pragma unroll
    for (int j = 0; j < 8; ++j) si_r[j] = form_s[f_own * 34 + 1 + fq * 8 + j];
    __syncthreads();

    // ---- xtab: p-outer, rs-vectorized b128 reads (overlays U) ----
    {
        v2f v02[8]; float sum[8], vs1[8];
        #pragma unroll
        for (int j = 0; j < 8; ++j) { v02[j].x = 0.f; v02[j].y = 0.f; sum[j] = 0.f; vs1[j] = 0.f; }
        const float4* m4  = (const float4*)S.match_s;
        const float4* rl4 = (const float4*)rlI;
        #pragma unroll
        for (int p = 0; p < 16; ++p) {
            float4 ma = m4[p * 8 + fq * 2], mb = m4[p * 8 + fq * 2 + 1];
            float mm[8] = {ma.x, ma.y, ma.z, ma.w, mb.x, mb.y, mb.z, mb.w};
            float4 ra = rl4[p * 16 + fq * 4],     rb2 = rl4[p * 16 + fq * 4 + 1];
            float4 rc = rl4[p * 16 + fq * 4 + 2], rd  = rl4[p * 16 + fq * 4 + 3];
            float rl[16] = {ra.x, ra.y, ra.z, ra.w, rb2.x, rb2.y, rb2.z, rb2.w,
                            rc.x, rc.y, rc.z, rc.w, rd.x, rd.y, rd.z, rd.w};
            #pragma unroll
            for (int j = 0; j < 8; ++j) {
                v02[j].x += rl[2 * j]     * vepf[p].x;
                v02[j].y += rl[2 * j + 1] * vepf[p].y;
                float wc = mm[j] * wchf[p];
                sum[j] += wc;
                vs1[j] += fmaxf(wc, 0.f) * vchf[p];
            }
        }
        #pragma unroll
        for (int j = 0; j < 8; ++j) {
            int rs = fq * 8 + j;
            float pch = sigm(sum[j] - wncf);
            float si  = si_r[j];
            xtab[rs * 64 + f_own]        = v02[j].x;
            xtab[2048 + rs * 64 + f_own] = si + pch * (vs1[j] - si);
            xtab[4096 + rs * 64 + f_own] = v02[j].y;
        }
    }
    __syncthreads();

    // ---- k-ordered coefs (k = rs*3+sub) + exclusive prefix (posn) ----
    float* ck_s  = S.match_s;        // match dead after xtab
    float* pos_s = S.match_s + 128;
    if (t < 96) ck_s[t] = S.coef_s[(t % 3) * 32 + (t / 3)];
    __syncthreads();
    if (t < 64) {
        float a = ck_s[t];
        float a0 = a;
        #pragma unroll
        for (int d = 1; d < 64; d <<= 1) { float v = __shfl_up(a, d, 64); if (t >= d) a += v; }
        pos_s[t] = a - a0;                          // exclusive prefix
        float carry = __shfl(a, 63, 64);
        float b2 = (t < 32) ? ck_s[64 + t] : 0.f;
        float c2 = b2;
        #pragma unroll
        for (int d = 1; d < 32; d <<= 1) { float v = __shfl_up(c2, d, 32); if ((t & 31) >= d) c2 += v; }
        if (t < 32) pos_s[64 + t] = carry + c2 - b2;
    }
    __syncthreads();

    // ---- gtab[k][r]: all 96 softmax-gates in parallel (overlays V) ----
    #pragma unroll 1
    for (int i = 0; i < 12; ++i) {
        int idx = t + 256 * i;
        int k = idx >> 5, r = idx & 31;
        float posn = pos_s[k];
        float pc = fminf(posn, 31.f);
        float ci = floorf(pc + 0.5f);
        float dmin = posn - ci;
        float dd = posn - (float)r;
        float eo = __expf(-2.f * (dd * dd - dmin * dmin));   // exact, max-subtracted
        float Z = eo;
        Z += __shfl_xor(Z, 1, 32);
        Z += __shfl_xor(Z, 2, 32);
        Z += __shfl_xor(Z, 4, 32);
        Z += __shfl_xor(Z, 8, 32);
        Z += __shfl_xor(Z, 16, 32);
        gtab[idx] = ck_s[k] * eo / Z;
    }
    __syncthreads();

    // ---- phase D: pure-throughput blend ----
    const int fgrp = t >> 5;
    v2f o01, o23, o45, o67;
    o01 = 0.f; o23 = 0.f; o45 = 0.f; o67 = 0.f;
    #pragma unroll 1
    for (int rs = 0; rs < 32; ++rs) {
        #pragma unroll
        for (int sub = 0; sub < 3; ++sub) {
            float g = gtab[(rs * 3 + sub) * 32 + my_r];
            v2f gv; gv.x = g; gv.y = g;
            const float4* xb = (const float4*)(xtab + sub * 2048 + rs * 64 + fgrp * 8);
            float4 xa = xb[0], xc = xb[1];
            v2f x01, x23, x45, x67;
            x01.x = xa.x; x01.y = xa.y; x23.x = xa.z; x23.y = xa.w;
            x45.x = xc.x; x45.y = xc.y; x67.x = xc.z; x67.y = xc.w;
            o01 += gv * (x01 - o01);
            o23 += gv * (x23 - o23);
            o45 += gv * (x45 - o45);
            o67 += gv * (x67 - o67);
        }
    }

    float oreg[8] = {o01.x, o01.y, o23.x, o23.y, o45.x, o45.y, o67.x, o67.y};
    #pragma unroll
    for (int i = 0; i < 8; ++i) {
        ST<F32>(A.outp, b * 2048 + (fgrp * 8 + i) * 32 + my_r, oreg[i]);
    }
}

__global__ __launch_bounds__(256) void scan_kernel(Args A, const float* Y) {
    __shared__ ScanSmem S;
    __shared__ int dt_s;
    const int t = threadIdx.x, b = blockIdx.x;
    int isf32 = probe_is_f32(A.ctx, t, &dt_s);
    if (isf32) scan_body<true>(S, t, b, A, Y);
    else       scan_body<false>(S, t, b, A, Y);
}

// ---------------- Last-resort monolithic fallback (round-2, proven) ---------
struct Smem {
    float U[6144];
    float form_s[64 * 33];
    float match_s[512];
    float wch_s[1024];
    float vch_s[1024];
    float vep0_s[1024];
    float vep2_s[1024];
    float wep0_s[16], wep2_s[16], wdl_s[16];
    float wnc_s[64];
    float sc_s[2];
    float ssum_s[96];
};

template<bool F32>
__device__ void mono_body(Smem& S, int t, int b, const Args& A) {
    float* c_s  = S.U;
    float* modl = S.U + 128;
    float* Wk_s = S.U + 224;
    float* bk_s = S.U + 3344;
    float* xtab = S.U;

    if (t < 128) c_s[t] = LD<F32>(A.ctx, b * 128 + t);
    {
        int e0 = b * 2048 + t * 8;
        float4 x = LD4<F32>(A.form, e0);
        float4 y = LD4<F32>(A.form, e0 + 4);
        int f = t >> 2, r0 = (t & 3) * 8;
        float* dst = S.form_s + f * 33 + r0;
        dst[0] = x.x; dst[1] = x.y; dst[2] = x.z; dst[3] = x.w;
        dst[4] = y.x; dst[5] = y.y; dst[6] = y.z; dst[7] = y.w;
    }
    __syncthreads();
    if (t < 96) {
        float a = LD<F32>(A.mod_b, t);
        for (int cc = 0; cc < 128; ++cc) a += c_s[cc] * LD<F32>(A.mod_W, cc * 96 + t);
        modl[t] = a;
    }
    __syncthreads();
    if (t < 16) {
        float v[6]; float mx = -1e30f;
        #pragma unroll
        for (int j = 0; j < 6; ++j) { v[j] = modl[t * 6 + j]; mx = fmaxf(mx, v[j]); }
        float s = 0.f;
        #pragma unroll
        for (int j = 0; j < 6; ++j) { v[j] = __expf(v[j] - mx); s += v[j]; }
        float inv = 1.f / s;
        #pragma unroll
        for (int j = 0; j < 6; ++j) modl[t * 6 + j] = v[j] * inv;
    }
    __syncthreads();
    for (int j = t; j < 512; j += 256) {
        int n0 = j * 2;
        float2 bb = LD2<F32>(A.wch_b, n0);
        float a0 = bb.x, a1 = bb.y;
        for (int cc = 0; cc < 128; ++cc) {
            float2 w = LD2<F32>(A.wch_W, cc * 1024 + n0); float cv = c_s[cc];
            a0 += cv * w.x; a1 += cv * w.y;
        }
        int p = n0 >> 6; float sc = modl[p * 6 + 0];
        S.wch_s[n0] = sc * a0; S.wch_s[n0 + 1] = sc * a1;
    }
    for (int j = t; j < 512; j += 256) {
        int n0 = j * 2;
        float2 bb = LD2<F32>(A.vch_b, n0);
        float a0 = bb.x, a1 = bb.y;
        for (int cc = 0; cc < 128; ++cc) {
            float2 w = LD2<F32>(A.vch_W, cc * 1024 + n0); float cv = c_s[cc];
            a0 += cv * w.x; a1 += cv * w.y;
        }
        S.vch_s[n0] = a0; S.vch_s[n0 + 1] = a1;
    }
    for (int u = t; u < 1024; u += 256) {
        int n0 = u * 4;
        float4 bb = LD4<F32>(A.vep_b, n0);
        float a0 = bb.x, a2 = bb.z;
        for (int cc = 0; cc < 128; ++cc) {
            float4 w = LD4<F32>(A.vep_W, cc * 4096 + n0); float cv = c_s[cc];
            a0 += cv * w.x; a2 += cv * w.z;
        }
        S.vep0_s[u] = a0; S.vep2_s[u] = a2;
    }
    for (int j = t; j < 1536; j += 256) {
        int k  = j >> 9;
        int jj = j & 511;
        int n0 = jj * 2;
        float2 bb = LD2<F32>(A.m_Wb, k * 1024 + n0);
        float a0 = bb.x, a1 = bb.y;
        for (int cc = 0; cc < 128; ++cc) {
            float2 w = LD2<F32>(A.m_W, (k * 128 + cc) * 1024 + n0); float cv = c_s[cc];
            a0 += cv * w.x; a1 += cv * w.y;
        }
        int p = n0 >> 6, f = n0 & 63;
        Wk_s[(k * 16 + p) * 65 + f]     = a0;
        Wk_s[(k * 16 + p) * 65 + f + 1] = a1;
    }
    if (t < 16) {
        int n0 = t * 4;
        float4 bb = LD4<F32>(A.wep_b, n0);
        float a0 = bb.x, a2 = bb.z;
        for (int cc = 0; cc < 128; ++cc) {
            float4 w = LD4<F32>(A.wep_W, cc * 64 + n0); float cv = c_s[cc];
            a0 += cv * w.x; a2 += cv * w.z;
        }
        S.wep0_s[t] = modl[t * 6 + 2] * a0;
        S.wep2_s[t] = modl[t * 6 + 4] * a2;
    } else if (t < 32) {
        int p = t - 16;
        float a = LD<F32>(A.wdl_b, p);
        for (int cc = 0; cc < 128; ++cc) a += c_s[cc] * LD<F32>(A.wdl_W, cc * 16 + p);
        S.wdl_s[p] = modl[p * 6 + 1] * a;
    } else if (t < 96) {
        int f = t - 32;
        float a = LD<F32>(A.wnc_b, f);
        for (int cc = 0; cc < 128; ++cc) a += c_s[cc] * LD<F32>(A.wnc_W, cc * 64 + f);
        S.wnc_s[f] = __expf(a);
    } else if (t < 98) {
        const void* W  = (t == 96) ? A.wnd_W : A.wne_W;
        const void* bb = (t == 96) ? A.wnd_b : A.wne_b;
        float a = LD<F32>(bb, 0);
        for (int cc = 0; cc < 128; ++cc) a += c_s[cc] * LD<F32>(W, cc);
        S.sc_s[t - 96] = __expf(a);
    } else if (t < 146) {
        int i = t - 98;
        int k = i >> 4, p = i & 15;
        float a = LD<F32>(A.mb_b, k * 16 + p);
        for (int cc = 0; cc < 128; ++cc) a += c_s[cc] * LD<F32>(A.mb_W, (k * 128 + cc) * 16 + p);
        bk_s[i] = a;
    }
    __syncthreads();
    for (int idx = t; idx < 512; idx += 256) {
        int p = idx >> 5, r = idx & 31;
        float s0 = bk_s[p], s1 = bk_s[16 + p], s2 = bk_s[32 + p];
        const float* w0 = Wk_s + p * 65;
        const float* w1 = Wk_s + (16 + p) * 65;
        const float* w2 = Wk_s + (32 + p) * 65;
        for (int f = 0; f < 64; ++f) {
            const float* fr = S.form_s + f * 33 + r;
            float fm1 = (r > 0)  ? fr[-1] : 0.f;
            float f0  = fr[0];
            float fp1 = (r < 31) ? fr[1]  : 0.f;
            s0 += w0[f] * fm1; s1 += w1[f] * f0; s2 += w2[f] * fp1;
        }
        S.match_s[p * 32 + r] = __expf(lsg(s0) + lsg(s1) + lsg(s2));
    }
    __syncthreads();
    if (t < 96) {
        int which = t >> 5, r = t & 31;
        const float* w = (which == 0) ? S.wep0_s : (which == 1) ? S.wep2_s : S.wdl_s;
        float s = 0.f;
        for (int p = 0; p < 16; ++p) s += S.match_s[p * 32 + r] * w[p];
        S.ssum_s[which * 32 + r] = s;
    }
    #pragma unroll 1
    for (int q = 0; q < 24; ++q) {
        int idx = t + 256 * q;
        int sub = idx >> 11;
        int rs  = (idx >> 6) & 31;
        int f   = idx & 63;
        float x;
        if (sub == 1) {
            float sum = 0.f, vs = 0.f;
            for (int p = 0; p < 16; ++p) {
                float wc = S.match_s[p * 32 + rs] * S.wch_s[p * 64 + f];
                sum += wc;
                vs  += fmaxf(wc, 0.f) * S.vch_s[p * 64 + f];
            }
            float pch = sigm(sum - S.wnc_s[f]);
            float si  = S.form_s[f * 33 + rs];
            x = si + pch * (vs - si);
        } else {
            const float* wep = (sub == 0) ? S.wep0_s : S.wep2_s;
            const float* vep = (sub == 0) ? S.vep0_s : S.vep2_s;
            float vs = 0.f;
            for (int p = 0; p < 16; ++p) {
                float w = S.match_s[p * 32 + rs] * wep[p];
                vs += fmaxf(w, 0.f) * vep[p * 64 + f];
            }
            x = vs;
        }
        xtab[idx] = x;
    }
    __syncthreads();
    const int my_r = t & 31;
    const int fgrp = t >> 5;
    float oreg[8];
    #pragma unroll
    for (int i = 0; i < 8; ++i) oreg[i] = 0.f;
    float posn = 0.f;
    const float wnd1v = S.sc_s[0];
    const float wne1v = S.sc_s[1];
    for (int rs = 0; rs < 32; ++rs) {
        #pragma unroll
        for (int sub = 0; sub < 3; ++sub) {
            float coef;
            if (sub == 1) coef = 1.f - sigm(S.ssum_s[64 + rs] - wnd1v);
            else          coef = sigm(S.ssum_s[(sub & 2) * 16 + rs] - wne1v);
            float pc = fminf(posn, 31.f);
            int ci = (int)(pc + 0.5f);
            int lo = ci - 4; if (lo < 0)  lo = 0;
            int hi = ci + 4; if (hi > 31) hi = 31;
            float dmin = posn - (float)ci;
            float mx = -2.f * dmin * dmin;
            float Z = 0.f, eo = 0.f;
            for (int r = lo; r <= hi; ++r) {
                float d = posn - (float)r;
                float e = __expf(-2.f * d * d - mx);
                Z += e;
                if (r == my_r) eo = e;
            }
            float g = coef * eo / Z;
            const float* xb = xtab + (sub * 2048 + rs * 64 + fgrp * 8);
            #pragma unroll
            for (int i = 0; i < 8; ++i) oreg[i] += g * (xb[i] - oreg[i]);
            posn += coef;
        }
    }
    #pragma unroll
    for (int i = 0; i < 8; ++i) {
        ST<F32>(A.outp, b * 2048 + (fgrp * 8 + i) * 32 + my_r, oreg[i]);
    }
}

__global__ __launch_bounds__(256) void phon_mono(Args A) {
    __shared__ Smem S;
    __shared__ int dt_s;
    const int t = threadIdx.x, b = blockIdx.x;
    int isf32 = probe_is_f32(A.ctx, t, &dt_s);
    if (isf32) mono_body<true>(S, t, b, A);
    else       mono_body<false>(S, t, b, A);
}

extern "C" void kernel_launch(void* const* d_in, const int* in_sizes, int n_in,
                              void* d_out, int out_size, void* d_ws, size_t ws_size,
                              hipStream_t stream) {
    Args A;
    A.form  = d_in[0];  A.ctx   = d_in[1];
    A.mod_W = d_in[2];  A.mod_b = d_in[3];
    A.wch_W = d_in[4];  A.wch_b = d_in[5];
    A.wdl_W = d_in[6];  A.wdl_b = d_in[7];
    A.wep_W = d_in[8];  A.wep_b = d_in[9];
    A.vch_W = d_in[10]; A.vch_b = d_in[11];
    A.vep_W = d_in[12]; A.vep_b = d_in[13];
    A.wnc_W = d_in[14]; A.wnc_b = d_in[15];
    A.wnd_W = d_in[16]; A.wnd_b = d_in[17];
    A.wne_W = d_in[18]; A.wne_b = d_in[19];
    A.m_W   = d_in[20]; A.m_Wb  = d_in[21];
    A.mb_W  = d_in[22]; A.mb_b  = d_in[23];
    A.outp  = d_out;

    const size_t yElems  = (size_t)B_ * YS3;        // floats
    const size_t bpElems = (size_t)NT * 4096;       // u16
    const size_t need = yElems * 4 + bpElems * 2 + (size_t)YS3 * 4;
    if (ws_size >= need) {
        float* Y     = (float*)d_ws;
        u16*   Bpack = (u16*)(Y + yElems);
        float* bcat  = (float*)(Bpack + bpElems);
        packw_kernel<<<NT, 256, 0, stream>>>(A, Bpack, bcat);
        gemm_mfma_kernel<<<30 * 128, 256, 0, stream>>>(A, Bpack, bcat, Y);
        scan_kernel<<<B_, 256, 0, stream>>>(A, Y);
    } else {
        phon_mono<<<B_, 256, 0, stream>>>(A);
    }
}